// Round 12
// baseline (254.579 us; speedup 1.0000x reference)
//
#include <hip/hip_runtime.h>
#include <cfloat>

#define NN 50000
#define EE 1600000
#define NEG 0.2f
#define BSH 7
#define BSZ 128                       // nodes per bucket
#define NBK ((NN + BSZ - 1) / BSZ)    // 391
#define CAPB 4608                     // fixed bucket capacity (mean 4096 + 8 sigma)
#define TSZ 8192                      // k_bin tile size (edges)
#define NT  ((EE + TSZ - 1) / TSZ)    // 196 tiles per list

__device__ inline float leaky(float v) { return v >= 0.f ? v : NEG * v; }

__device__ inline unsigned short f2bf(float f) {
    unsigned u = __float_as_uint(f);
    u += 0x7FFFu + ((u >> 16) & 1u);          // round-to-nearest-even
    return (unsigned short)(u >> 16);
}
__device__ inline float bf2f(unsigned short s) {
    return __uint_as_float(((unsigned)s) << 16);
}

// ---------------------------------------------------------------------------
// GEMM: h16 = bf16(feat@Wg+bg) ; hp16 = bf16(feat@Wp+bp) ; ssrc/sdst f32.
// Also zeroes the bucket cursor array.
__global__ __launch_bounds__(256) void k_gemm(
    const float* __restrict__ feat, const float* __restrict__ Wg,
    const float* __restrict__ bg, const float* __restrict__ as_,
    const float* __restrict__ ad_, const float* __restrict__ Wp,
    const float* __restrict__ bp,
    unsigned short* __restrict__ h16, unsigned short* __restrict__ hp16,
    float* __restrict__ ssrc, float* __restrict__ sdst,
    int* __restrict__ cnt)
{
    __shared__ float sWg[64 * 64];
    __shared__ float sWp[64 * 64];
    __shared__ float sb[4 * 64];
    int t = threadIdx.x;
    int gid = blockIdx.x * 256 + t;
    if (gid < 3 * NBK * 16) cnt[gid] = 0;
    for (int i = t; i < 4096; i += 256) { sWg[i] = Wg[i]; sWp[i] = Wp[i]; }
    if (t < 64)       sb[t] = bg[t];
    else if (t < 128) sb[t] = bp[t - 64];
    else if (t < 192) sb[t] = as_[t - 128];
    else              sb[t] = ad_[t - 192];
    __syncthreads();

    int lane = t & 63;
    int w    = t >> 6;
    int nw   = (gridDim.x * blockDim.x) >> 6;
    for (int n = blockIdx.x * 4 + w; n < NN; n += nw) {
        float fv   = feat[n * 64 + lane];
        float accg = sb[lane];
        float accp = sb[64 + lane];
#pragma unroll
        for (int k = 0; k < 64; ++k) {
            float f = __shfl(fv, k, 64);
            accg = fmaf(f, sWg[k * 64 + lane], accg);
            accp = fmaf(f, sWp[k * 64 + lane], accp);
        }
        h16 [n * 64 + lane] = f2bf(accg);
        hp16[n * 64 + lane] = f2bf(accp);
        float vs = accg * sb[128 + lane];
        float vd = accg * sb[192 + lane];
#pragma unroll
        for (int off = 32; off > 0; off >>= 1) {
            vs += __shfl_xor(vs, off, 64);
            vd += __shfl_xor(vd, off, 64);
        }
        if (lane == 0) { ssrc[n] = vs; sdst[n] = vd; }
    }
}

// ---------------------------------------------------------------------------
// tile-local bucket sort + chunk reservation into fixed-capacity regions.
// GAT payload: src | dst<<16.  p staging: tile_local_idx | dst<<16, with
// src/val re-read from the (L2-hot) tile window at writeout. bgpv is bf16.
__global__ __launch_bounds__(256) void k_bin(
    const int* __restrict__ lu, const int* __restrict__ ld,
    const int* __restrict__ pi, const float* __restrict__ pv,
    int* __restrict__ cnt,
    unsigned* __restrict__ bglu, unsigned* __restrict__ bgld,
    unsigned* __restrict__ bgpc, unsigned short* __restrict__ bgpv)
{
    __shared__ int hist[NBK];
    __shared__ int loff[NBK];
    __shared__ int gbase[NBK];
    __shared__ int part[256];
    __shared__ unsigned stage[TSZ];
    int t = threadIdx.x;
    int task = blockIdx.x;
    int list = task / NT, tile = task - list * NT;
    int e0 = tile * TSZ, e1 = min(e0 + TSZ, EE), sz = e1 - e0;
    const int* srcp; const int* dstp;
    if (list == 0)      { srcp = lu;      dstp = lu + EE; }
    else if (list == 1) { srcp = ld;      dstp = ld + EE; }
    else                { srcp = pi + EE; dstp = pi; }
    for (int i = t; i < NBK; i += 256) hist[i] = 0;
    __syncthreads();
    for (int i = t; i < sz; i += 256)
        atomicAdd(&hist[dstp[e0 + i] >> BSH], 1);
    __syncthreads();
    {
        const int CH = (NBK + 255) / 256;
        int lo = t * CH, hi = min(lo + CH, NBK);
        int s = 0;
        for (int i = lo; i < hi; ++i) s += hist[i];
        part[t] = s;
        __syncthreads();
        for (int d = 1; d < 256; d <<= 1) {
            int v = 0;
            if (t >= d) v = part[t - d];
            __syncthreads();
            if (t >= d) part[t] += v;
            __syncthreads();
        }
        int run = (t == 0) ? 0 : part[t - 1];
        for (int i = lo; i < hi; ++i) { loff[i] = run; run += hist[i]; }
    }
    __syncthreads();
    for (int i = t; i < NBK; i += 256) {
        int c = hist[i];
        if (c) {
            int pos = atomicAdd(&cnt[(list * NBK + i) * 16], c);
            gbase[i] = i * CAPB + pos;
        }
        hist[i] = loff[i];
    }
    __syncthreads();
    if (list == 2) {
        for (int i = t; i < sz; i += 256) {
            int d = dstp[e0 + i];
            unsigned pay = (unsigned)i | ((unsigned)d << 16);
            int r = atomicAdd(&hist[d >> BSH], 1);
            stage[r] = pay;
        }
        __syncthreads();
        for (int i = t; i < sz; i += 256) {
            unsigned v = stage[i];
            int b = (int)(v >> (16 + BSH));
            int li = (int)(v & 0xFFFFu);
            int addr = gbase[b] + (i - loff[b]);
            bgpc[addr] = (unsigned)srcp[e0 + li] | (v & 0xFFFF0000u);
            bgpv[addr] = f2bf(pv[e0 + li]);
        }
    } else {
        for (int i = t; i < sz; i += 256) {
            int d = dstp[e0 + i];
            unsigned pay = (unsigned)srcp[e0 + i] | ((unsigned)d << 16);
            int r = atomicAdd(&hist[d >> BSH], 1);
            stage[r] = pay;
        }
        __syncthreads();
        unsigned* arr = list ? bgld : bglu;
        for (int i = t; i < sz; i += 256) {
            unsigned v = stage[i];
            int b = (int)(v >> (16 + BSH));
            arr[gbase[b] + (i - loff[b])] = v;
        }
    }
}

// ---------------------------------------------------------------------------
// fused per-bucket GAT gather: counting-sort bucket edges per node in LDS
// (both lists), then 8 waves x 16 nodes register-gather (16-lane rows,
// 4 edges/instr).
__global__ __launch_bounds__(512) void k_ggat(
    const int* __restrict__ cnt,
    const unsigned* __restrict__ bglu, const unsigned* __restrict__ bgld,
    const float* __restrict__ ssrc, const float* __restrict__ sdst,
    const unsigned short* __restrict__ h16, float* __restrict__ out)
{
    __shared__ unsigned buf[CAPB];
    __shared__ unsigned short arr0[CAPB];
    __shared__ unsigned short arr1[CAPB];
    __shared__ int ecnt[BSZ];
    __shared__ int scn[BSZ];
    __shared__ int eoff[2][BSZ + 1];
    int b = blockIdx.x;
    int t = threadIdx.x;
    // --- counting-sort both lists into per-node order in LDS ---
    for (int l = 0; l < 2; ++l) {
        const unsigned* g = (l ? bgld : bglu) + (size_t)b * CAPB;
        int size = min(cnt[(l * NBK + b) * 16], CAPB);
        if (t < BSZ) ecnt[t] = 0;
        __syncthreads();
        for (int i = t; i < size; i += 512) {
            unsigned v = g[i];
            buf[i] = v;
            atomicAdd(&ecnt[(v >> 16) & (BSZ - 1)], 1);
        }
        __syncthreads();
        if (t < BSZ) scn[t] = ecnt[t];
        __syncthreads();
        for (int d = 1; d < BSZ; d <<= 1) {
            int add = 0;
            if (t < BSZ && t >= d) add = scn[t - d];
            __syncthreads();
            if (t < BSZ && t >= d) scn[t] += add;
            __syncthreads();
        }
        if (t < BSZ) {
            int excl = scn[t] - ecnt[t];
            eoff[l][t] = excl;
            if (t == BSZ - 1) eoff[l][BSZ] = scn[t];
            ecnt[t] = excl;                  // cursors
        }
        __syncthreads();
        unsigned short* arr = l ? arr1 : arr0;
        for (int i = t; i < size; i += 512) {
            unsigned v = buf[i];
            int pos = atomicAdd(&ecnt[(v >> 16) & (BSZ - 1)], 1);
            arr[pos] = (unsigned short)(v & 0xFFFFu);
        }
        __syncthreads();
    }
    // --- gather: 8 waves x 16 nodes ---
    int lane = t & 63, w = t >> 6;
    int grp = lane >> 4, cid = lane & 15;
    for (int dl = w * 16; dl < w * 16 + 16; ++dl) {
        int n = (b << BSH) + dl;
        if (n >= NN) continue;
        float sd = sdst[n];
        float t0 = 0.f, t1 = 0.f, t2 = 0.f, t3 = 0.f;
        for (int l = 0; l < 2; ++l) {
            const unsigned short* arr = l ? arr1 : arr0;
            int bs = eoff[l][dl], deg = eoff[l][dl + 1] - bs;
            if (deg <= 0) continue;
            float p0 = 0.f, p1 = 0.f, p2 = 0.f, p3 = 0.f;
            float q0 = 0.f, q1 = 0.f, q2 = 0.f, q3 = 0.f, den = 0.f;
            for (int cb = 0; cb < deg; cb += 64) {
                int j  = cb + lane;
                int jc = min(j, deg - 1);
                int sl = (int)arr[bs + jc];
                float ex = 0.f;
                if (j < deg) { ex = __expf(leaky(ssrc[sl] + sd)); den += ex; }
                int c64 = min(64, deg - cb);
#pragma unroll 2
                for (int k = 0; k < c64; k += 8) {
                    int i0 = k + grp, i1 = k + 4 + grp;
                    int   s0 = __shfl(sl, i0, 64);
                    int   s1 = __shfl(sl, i1, 64);
                    float w0 = __shfl(ex, i0, 64);
                    float w1 = __shfl(ex, i1, 64);
                    uint2 r0 = *reinterpret_cast<const uint2*>(h16 + (size_t)s0 * 64 + cid * 4);
                    uint2 r1 = *reinterpret_cast<const uint2*>(h16 + (size_t)s1 * 64 + cid * 4);
                    p0 = fmaf(w0, __uint_as_float(r0.x << 16), p0);
                    p1 = fmaf(w0, __uint_as_float(r0.x & 0xFFFF0000u), p1);
                    p2 = fmaf(w0, __uint_as_float(r0.y << 16), p2);
                    p3 = fmaf(w0, __uint_as_float(r0.y & 0xFFFF0000u), p3);
                    q0 = fmaf(w1, __uint_as_float(r1.x << 16), q0);
                    q1 = fmaf(w1, __uint_as_float(r1.x & 0xFFFF0000u), q1);
                    q2 = fmaf(w1, __uint_as_float(r1.y << 16), q2);
                    q3 = fmaf(w1, __uint_as_float(r1.y & 0xFFFF0000u), q3);
                }
            }
#pragma unroll
            for (int o = 32; o; o >>= 1) den += __shfl_xor(den, o, 64);
            float inv = 1.f / (den + 1e-16f);
            p0 += q0; p1 += q1; p2 += q2; p3 += q3;
            p0 += __shfl_xor(p0, 16, 64); p0 += __shfl_xor(p0, 32, 64);
            p1 += __shfl_xor(p1, 16, 64); p1 += __shfl_xor(p1, 32, 64);
            p2 += __shfl_xor(p2, 16, 64); p2 += __shfl_xor(p2, 32, 64);
            p3 += __shfl_xor(p3, 16, 64); p3 += __shfl_xor(p3, 32, 64);
            t0 = fmaf(p0, inv, t0); t1 = fmaf(p1, inv, t1);
            t2 = fmaf(p2, inv, t2); t3 = fmaf(p3, inv, t3);
        }
        if (lane < 16) {
            float4 o4; o4.x = t0; o4.y = t1; o4.z = t2; o4.w = t3;
            *reinterpret_cast<float4*>(out + (size_t)n * 64 + cid * 4) = o4;
        }
    }
}

// ---------------------------------------------------------------------------
// fused per-bucket p-list SpMM gather; accumulates into out (RMW).
__global__ __launch_bounds__(512) void k_gp(
    const int* __restrict__ cnt,
    const unsigned* __restrict__ bgpc, const unsigned short* __restrict__ bgpv,
    const unsigned short* __restrict__ hp16, float* __restrict__ out)
{
    __shared__ unsigned buf[CAPB];
    __shared__ unsigned short arrc[CAPB];
    __shared__ unsigned short arrv[CAPB];
    __shared__ int ecnt[BSZ];
    __shared__ int scn[BSZ];
    __shared__ int eoff[BSZ + 1];
    int b = blockIdx.x;
    int t = threadIdx.x;
    const unsigned* gc = bgpc + (size_t)b * CAPB;
    const unsigned short* gv = bgpv + (size_t)b * CAPB;
    int size = min(cnt[(2 * NBK + b) * 16], CAPB);
    if (t < BSZ) ecnt[t] = 0;
    __syncthreads();
    for (int i = t; i < size; i += 512) {
        unsigned v = gc[i];
        buf[i] = v;
        atomicAdd(&ecnt[(v >> 16) & (BSZ - 1)], 1);
    }
    __syncthreads();
    if (t < BSZ) scn[t] = ecnt[t];
    __syncthreads();
    for (int d = 1; d < BSZ; d <<= 1) {
        int add = 0;
        if (t < BSZ && t >= d) add = scn[t - d];
        __syncthreads();
        if (t < BSZ && t >= d) scn[t] += add;
        __syncthreads();
    }
    if (t < BSZ) {
        int excl = scn[t] - ecnt[t];
        eoff[t] = excl;
        if (t == BSZ - 1) eoff[BSZ] = scn[t];
        ecnt[t] = excl;
    }
    __syncthreads();
    for (int i = t; i < size; i += 512) {
        unsigned v = buf[i];
        int pos = atomicAdd(&ecnt[(v >> 16) & (BSZ - 1)], 1);
        arrc[pos] = (unsigned short)(v & 0xFFFFu);
        arrv[pos] = gv[i];
    }
    __syncthreads();
    int lane = t & 63, w = t >> 6;
    int grp = lane >> 4, cid = lane & 15;
    for (int dl = w * 16; dl < w * 16 + 16; ++dl) {
        int n = (b << BSH) + dl;
        if (n >= NN) continue;
        int bs = eoff[dl], deg = eoff[dl + 1] - bs;
        float p0 = 0.f, p1 = 0.f, p2 = 0.f, p3 = 0.f;
        float q0 = 0.f, q1 = 0.f, q2 = 0.f, q3 = 0.f;
        for (int cb = 0; cb < deg; cb += 64) {
            int j  = cb + lane;
            int jc = min(j, deg - 1);
            int cl = (int)arrc[bs + jc];
            float vl = (j < deg) ? bf2f(arrv[bs + jc]) : 0.f;
            int c64 = min(64, deg - cb);
#pragma unroll 2
            for (int k = 0; k < c64; k += 8) {
                int i0 = k + grp, i1 = k + 4 + grp;
                int   c0 = __shfl(cl, i0, 64);
                int   c1 = __shfl(cl, i1, 64);
                float w0 = __shfl(vl, i0, 64);
                float w1 = __shfl(vl, i1, 64);
                uint2 r0 = *reinterpret_cast<const uint2*>(hp16 + (size_t)c0 * 64 + cid * 4);
                uint2 r1 = *reinterpret_cast<const uint2*>(hp16 + (size_t)c1 * 64 + cid * 4);
                p0 = fmaf(w0, __uint_as_float(r0.x << 16), p0);
                p1 = fmaf(w0, __uint_as_float(r0.x & 0xFFFF0000u), p1);
                p2 = fmaf(w0, __uint_as_float(r0.y << 16), p2);
                p3 = fmaf(w0, __uint_as_float(r0.y & 0xFFFF0000u), p3);
                q0 = fmaf(w1, __uint_as_float(r1.x << 16), q0);
                q1 = fmaf(w1, __uint_as_float(r1.x & 0xFFFF0000u), q1);
                q2 = fmaf(w1, __uint_as_float(r1.y << 16), q2);
                q3 = fmaf(w1, __uint_as_float(r1.y & 0xFFFF0000u), q3);
            }
        }
        p0 += q0; p1 += q1; p2 += q2; p3 += q3;
        p0 += __shfl_xor(p0, 16, 64); p0 += __shfl_xor(p0, 32, 64);
        p1 += __shfl_xor(p1, 16, 64); p1 += __shfl_xor(p1, 32, 64);
        p2 += __shfl_xor(p2, 16, 64); p2 += __shfl_xor(p2, 32, 64);
        p3 += __shfl_xor(p3, 16, 64); p3 += __shfl_xor(p3, 32, 64);
        if (lane < 16) {
            float4 o4 = *reinterpret_cast<float4*>(out + (size_t)n * 64 + cid * 4);
            o4.x += p0; o4.y += p1; o4.z += p2; o4.w += p3;
            *reinterpret_cast<float4*>(out + (size_t)n * 64 + cid * 4) = o4;
        }
    }
}

// ---------------------------------------------------------------------------
extern "C" void kernel_launch(void* const* d_in, const int* in_sizes, int n_in,
                              void* d_out, int out_size, void* d_ws, size_t ws_size,
                              hipStream_t stream)
{
    const float* feat = (const float*)d_in[0];
    const float* Wg   = (const float*)d_in[1];
    const float* bg   = (const float*)d_in[2];
    const float* as_  = (const float*)d_in[3];
    const float* ad_  = (const float*)d_in[4];
    const float* Wp   = (const float*)d_in[5];
    const float* bp   = (const float*)d_in[6];
    const float* pv   = (const float*)d_in[7];
    const int*   lu   = (const int*)d_in[8];
    const int*   ld   = (const int*)d_in[9];
    const int*   pi   = (const int*)d_in[10];
    float* out = (float*)d_out;

    unsigned short* h16  = (unsigned short*)d_ws;        // NN*64 ushort
    unsigned short* hp16 = h16 + (size_t)NN * 64;        // NN*64 ushort
    float* fbase = (float*)(hp16 + (size_t)NN * 64);
    float* ssrc  = fbase;                                // NN
    float* sdst  = ssrc + NN;                            // NN
    int*   cnt   = (int*)(sdst + NN);                    // 3*NBK*16 (64B-padded)
    unsigned* bglu = (unsigned*)(cnt + 3 * NBK * 16);    // NBK*CAPB
    unsigned* bgld = bglu + (size_t)NBK * CAPB;          // NBK*CAPB
    unsigned* bgpc = bgld + (size_t)NBK * CAPB;          // NBK*CAPB
    unsigned short* bgpv = (unsigned short*)(bgpc + (size_t)NBK * CAPB); // NBK*CAPB ushort

    hipLaunchKernelGGL(k_gemm, dim3(2048), dim3(256), 0, stream,
                       feat, Wg, bg, as_, ad_, Wp, bp, h16, hp16, ssrc, sdst, cnt);
    hipLaunchKernelGGL(k_bin, dim3(3 * NT), dim3(256), 0, stream,
                       lu, ld, pi, pv, cnt, bglu, bgld, bgpc, bgpv);
    hipLaunchKernelGGL(k_ggat, dim3(NBK), dim3(512), 0, stream,
                       cnt, bglu, bgld, ssrc, sdst, h16, out);
    hipLaunchKernelGGL(k_gp, dim3(NBK), dim3(512), 0, stream,
                       cnt, bgpc, bgpv, hp16, out);
}

// Round 13
// 215.540 us; speedup vs baseline: 1.1811x; 1.1811x over previous
//
#include <hip/hip_runtime.h>
#include <cfloat>

#define NN 50000
#define EE 1600000
#define NEG 0.2f
#define BSH 7
#define BSZ 128                       // nodes per bucket
#define NBK ((NN + BSZ - 1) / BSZ)    // 391
#define CAPB 4608                     // fixed bucket capacity (mean 4096 + 8 sigma)
#define TSZ 8192                      // k_bin tile size (edges)
#define NT  ((EE + TSZ - 1) / TSZ)    // 196 tiles per list

__device__ inline float leaky(float v) { return v >= 0.f ? v : NEG * v; }

__device__ inline unsigned short f2bf(float f) {
    unsigned u = __float_as_uint(f);
    u += 0x7FFFu + ((u >> 16) & 1u);          // round-to-nearest-even
    return (unsigned short)(u >> 16);
}
__device__ inline float bf2f(unsigned short s) {
    return __uint_as_float(((unsigned)s) << 16);
}

// ---------------------------------------------------------------------------
// GEMM: h16 = bf16(feat@Wg+bg) ; hp16 = bf16(feat@Wp+bp) ; ssrc/sdst f32.
// Also zeroes the bucket cursor array.
__global__ __launch_bounds__(256) void k_gemm(
    const float* __restrict__ feat, const float* __restrict__ Wg,
    const float* __restrict__ bg, const float* __restrict__ as_,
    const float* __restrict__ ad_, const float* __restrict__ Wp,
    const float* __restrict__ bp,
    unsigned short* __restrict__ h16, unsigned short* __restrict__ hp16,
    float* __restrict__ ssrc, float* __restrict__ sdst,
    int* __restrict__ cnt)
{
    __shared__ float sWg[64 * 64];
    __shared__ float sWp[64 * 64];
    __shared__ float sb[4 * 64];
    int t = threadIdx.x;
    int gid = blockIdx.x * 256 + t;
    if (gid < 3 * NBK * 16) cnt[gid] = 0;
    for (int i = t; i < 4096; i += 256) { sWg[i] = Wg[i]; sWp[i] = Wp[i]; }
    if (t < 64)       sb[t] = bg[t];
    else if (t < 128) sb[t] = bp[t - 64];
    else if (t < 192) sb[t] = as_[t - 128];
    else              sb[t] = ad_[t - 192];
    __syncthreads();

    int lane = t & 63;
    int w    = t >> 6;
    int nw   = (gridDim.x * blockDim.x) >> 6;
    for (int n = blockIdx.x * 4 + w; n < NN; n += nw) {
        float fv   = feat[n * 64 + lane];
        float accg = sb[lane];
        float accp = sb[64 + lane];
#pragma unroll
        for (int k = 0; k < 64; ++k) {
            float f = __shfl(fv, k, 64);
            accg = fmaf(f, sWg[k * 64 + lane], accg);
            accp = fmaf(f, sWp[k * 64 + lane], accp);
        }
        h16 [n * 64 + lane] = f2bf(accg);
        hp16[n * 64 + lane] = f2bf(accp);
        float vs = accg * sb[128 + lane];
        float vd = accg * sb[192 + lane];
#pragma unroll
        for (int off = 32; off > 0; off >>= 1) {
            vs += __shfl_xor(vs, off, 64);
            vd += __shfl_xor(vd, off, 64);
        }
        if (lane == 0) { ssrc[n] = vs; sdst[n] = vd; }
    }
}

// ---------------------------------------------------------------------------
// tile-local bucket sort + chunk reservation into fixed-capacity regions.
// GAT payload: src | dst<<16.  p staging: tile_local_idx | dst<<16, with
// src/val re-read from the (L2-hot) tile window at writeout. bgpv is bf16.
__global__ __launch_bounds__(256) void k_bin(
    const int* __restrict__ lu, const int* __restrict__ ld,
    const int* __restrict__ pi, const float* __restrict__ pv,
    int* __restrict__ cnt,
    unsigned* __restrict__ bglu, unsigned* __restrict__ bgld,
    unsigned* __restrict__ bgpc, unsigned short* __restrict__ bgpv)
{
    __shared__ int hist[NBK];
    __shared__ int loff[NBK];
    __shared__ int gbase[NBK];
    __shared__ int part[256];
    __shared__ unsigned stage[TSZ];
    int t = threadIdx.x;
    int task = blockIdx.x;
    int list = task / NT, tile = task - list * NT;
    int e0 = tile * TSZ, e1 = min(e0 + TSZ, EE), sz = e1 - e0;
    const int* srcp; const int* dstp;
    if (list == 0)      { srcp = lu;      dstp = lu + EE; }
    else if (list == 1) { srcp = ld;      dstp = ld + EE; }
    else                { srcp = pi + EE; dstp = pi; }
    for (int i = t; i < NBK; i += 256) hist[i] = 0;
    __syncthreads();
    for (int i = t; i < sz; i += 256)
        atomicAdd(&hist[dstp[e0 + i] >> BSH], 1);
    __syncthreads();
    {
        const int CH = (NBK + 255) / 256;
        int lo = t * CH, hi = min(lo + CH, NBK);
        int s = 0;
        for (int i = lo; i < hi; ++i) s += hist[i];
        part[t] = s;
        __syncthreads();
        for (int d = 1; d < 256; d <<= 1) {
            int v = 0;
            if (t >= d) v = part[t - d];
            __syncthreads();
            if (t >= d) part[t] += v;
            __syncthreads();
        }
        int run = (t == 0) ? 0 : part[t - 1];
        for (int i = lo; i < hi; ++i) { loff[i] = run; run += hist[i]; }
    }
    __syncthreads();
    for (int i = t; i < NBK; i += 256) {
        int c = hist[i];
        if (c) {
            int pos = atomicAdd(&cnt[(list * NBK + i) * 16], c);
            gbase[i] = i * CAPB + pos;
        }
        hist[i] = loff[i];
    }
    __syncthreads();
    if (list == 2) {
        for (int i = t; i < sz; i += 256) {
            int d = dstp[e0 + i];
            unsigned pay = (unsigned)i | ((unsigned)d << 16);
            int r = atomicAdd(&hist[d >> BSH], 1);
            stage[r] = pay;
        }
        __syncthreads();
        for (int i = t; i < sz; i += 256) {
            unsigned v = stage[i];
            int b = (int)(v >> (16 + BSH));
            int li = (int)(v & 0xFFFFu);
            int addr = gbase[b] + (i - loff[b]);
            bgpc[addr] = (unsigned)srcp[e0 + li] | (v & 0xFFFF0000u);
            bgpv[addr] = f2bf(pv[e0 + li]);
        }
    } else {
        for (int i = t; i < sz; i += 256) {
            int d = dstp[e0 + i];
            unsigned pay = (unsigned)srcp[e0 + i] | ((unsigned)d << 16);
            int r = atomicAdd(&hist[d >> BSH], 1);
            stage[r] = pay;
        }
        __syncthreads();
        unsigned* arr = list ? bgld : bglu;
        for (int i = t; i < sz; i += 256) {
            unsigned v = stage[i];
            int b = (int)(v >> (16 + BSH));
            arr[gbase[b] + (i - loff[b])] = v;
        }
    }
}

// ---------------------------------------------------------------------------
// per-(list,bucket): refine bucket region to per-node CSR; emits packed
// poff = (region_start<<8)|deg and compact ushort payload arrays.
__global__ __launch_bounds__(256) void k_b2c(
    const int* __restrict__ cnt,
    const unsigned* __restrict__ bglu, const unsigned* __restrict__ bgld,
    const unsigned* __restrict__ bgpc, const unsigned short* __restrict__ bgpv,
    unsigned short* __restrict__ s_lu16, unsigned short* __restrict__ s_ld16,
    unsigned short* __restrict__ c16, unsigned short* __restrict__ v16,
    int* __restrict__ poff)
{
    __shared__ int ecnt[BSZ];
    __shared__ int scn[BSZ];
    __shared__ unsigned buf[CAPB];
    __shared__ unsigned short bufv[CAPB];
    int bid  = blockIdx.x;
    int list = bid / NBK, b = bid - list * NBK;
    int size = min(cnt[(list * NBK + b) * 16], CAPB);
    int base = b * CAPB;
    int t = threadIdx.x;
    if (t < BSZ) ecnt[t] = 0;
    __syncthreads();
    const unsigned* arr = (list == 0) ? bglu : (list == 1) ? bgld : bgpc;
    for (int i = t; i < size; i += 256) {
        unsigned v = arr[base + i];
        buf[i] = v;
        if (list == 2) bufv[i] = bgpv[base + i];
        atomicAdd(&ecnt[(v >> 16) & (BSZ - 1)], 1);
    }
    __syncthreads();
    if (t < BSZ) scn[t] = ecnt[t];
    __syncthreads();
    for (int d = 1; d < BSZ; d <<= 1) {
        int add = 0;
        if (t < BSZ && t >= d) add = scn[t - d];
        __syncthreads();
        if (t < BSZ && t >= d) scn[t] += add;
        __syncthreads();
    }
    int n0 = b << BSH;
    if (t < BSZ) {
        int deg  = ecnt[t];
        int excl = scn[t] - deg;
        if (n0 + t < NN)
            poff[list * NN + n0 + t] = ((base + excl) << 8) | deg;
    }
    __syncthreads();
    if (t < BSZ) ecnt[t] = scn[t] - ecnt[t];     // cursors
    __syncthreads();
    if (list == 2) {
        for (int i = t; i < size; i += 256) {
            unsigned v = buf[i];
            int pos = atomicAdd(&ecnt[(v >> 16) & (BSZ - 1)], 1);
            c16[base + pos] = (unsigned short)(v & 0xFFFFu);
            v16[base + pos] = bufv[i];
        }
    } else {
        unsigned short* o16 = list ? s_ld16 : s_lu16;
        for (int i = t; i < size; i += 256) {
            unsigned v = buf[i];
            int pos = atomicAdd(&ecnt[(v >> 16) & (BSZ - 1)], 1);
            o16[base + pos] = (unsigned short)(v & 0xFFFFu);
        }
    }
}

// ---------------------------------------------------------------------------
// GAT gather (lu+ld only; touches only h16 -> halved L2 working set).
// One wave per node; 16 edges per iteration via 4 independent uint2 loads;
// tail via clamped index + zero weight (no tail loop).
__global__ __launch_bounds__(256) void k_ggat(
    const int* __restrict__ poff,
    const unsigned short* __restrict__ s_lu16, const unsigned short* __restrict__ s_ld16,
    const float* __restrict__ ssrc, const float* __restrict__ sdst,
    const unsigned short* __restrict__ h16, float* __restrict__ out)
{
    int lane = threadIdx.x & 63;
    int grp  = lane >> 4;            // edge subgroup 0..3
    int cid  = lane & 15;            // channel-quad id
    int wid  = blockIdx.x * (blockDim.x >> 6) + (threadIdx.x >> 6);
    int nw   = gridDim.x * (blockDim.x >> 6);
    for (int n = wid; n < NN; n += nw) {
        float sd = sdst[n];
        float t0 = 0.f, t1 = 0.f, t2 = 0.f, t3 = 0.f;
        for (int list = 0; list < 2; ++list) {
            const unsigned short* ss = list ? s_ld16 : s_lu16;
            int word = poff[list * NN + n];
            int b = word >> 8, deg = word & 255;
            if (deg <= 0) continue;
            int e = b + deg;
            float pa0 = 0.f, pa1 = 0.f, pa2 = 0.f, pa3 = 0.f;
            float pb0 = 0.f, pb1 = 0.f, pb2 = 0.f, pb3 = 0.f;
            float pc0 = 0.f, pc1 = 0.f, pc2 = 0.f, pc3 = 0.f;
            float pd0 = 0.f, pd1 = 0.f, pd2 = 0.f, pd3 = 0.f, den = 0.f;
            for (int cb = b; cb < e; cb += 64) {
                int j  = cb + lane;
                int jc = min(j, e - 1);
                int sl = (int)ss[jc];
                float ex = 0.f;
                if (j < e) { ex = __expf(leaky(ssrc[sl] + sd)); den += ex; }
                int c64 = min(64, e - cb);
                for (int k = 0; k < c64; k += 16) {
                    int i0 = k + grp, i1 = k + 4 + grp;
                    int i2 = k + 8 + grp, i3 = k + 12 + grp;
                    int   s0 = __shfl(sl, i0, 64), s1 = __shfl(sl, i1, 64);
                    int   s2 = __shfl(sl, i2, 64), s3 = __shfl(sl, i3, 64);
                    float w0 = __shfl(ex, i0, 64), w1 = __shfl(ex, i1, 64);
                    float w2 = __shfl(ex, i2, 64), w3 = __shfl(ex, i3, 64);
                    uint2 r0 = *reinterpret_cast<const uint2*>(h16 + (size_t)s0 * 64 + cid * 4);
                    uint2 r1 = *reinterpret_cast<const uint2*>(h16 + (size_t)s1 * 64 + cid * 4);
                    uint2 r2 = *reinterpret_cast<const uint2*>(h16 + (size_t)s2 * 64 + cid * 4);
                    uint2 r3 = *reinterpret_cast<const uint2*>(h16 + (size_t)s3 * 64 + cid * 4);
                    pa0 = fmaf(w0, __uint_as_float(r0.x << 16), pa0);
                    pa1 = fmaf(w0, __uint_as_float(r0.x & 0xFFFF0000u), pa1);
                    pa2 = fmaf(w0, __uint_as_float(r0.y << 16), pa2);
                    pa3 = fmaf(w0, __uint_as_float(r0.y & 0xFFFF0000u), pa3);
                    pb0 = fmaf(w1, __uint_as_float(r1.x << 16), pb0);
                    pb1 = fmaf(w1, __uint_as_float(r1.x & 0xFFFF0000u), pb1);
                    pb2 = fmaf(w1, __uint_as_float(r1.y << 16), pb2);
                    pb3 = fmaf(w1, __uint_as_float(r1.y & 0xFFFF0000u), pb3);
                    pc0 = fmaf(w2, __uint_as_float(r2.x << 16), pc0);
                    pc1 = fmaf(w2, __uint_as_float(r2.x & 0xFFFF0000u), pc1);
                    pc2 = fmaf(w2, __uint_as_float(r2.y << 16), pc2);
                    pc3 = fmaf(w2, __uint_as_float(r2.y & 0xFFFF0000u), pc3);
                    pd0 = fmaf(w3, __uint_as_float(r3.x << 16), pd0);
                    pd1 = fmaf(w3, __uint_as_float(r3.x & 0xFFFF0000u), pd1);
                    pd2 = fmaf(w3, __uint_as_float(r3.y << 16), pd2);
                    pd3 = fmaf(w3, __uint_as_float(r3.y & 0xFFFF0000u), pd3);
                }
            }
#pragma unroll
            for (int o = 32; o; o >>= 1) den += __shfl_xor(den, o, 64);
            float inv = 1.f / (den + 1e-16f);
            float u0 = (pa0 + pb0) + (pc0 + pd0);
            float u1 = (pa1 + pb1) + (pc1 + pd1);
            float u2 = (pa2 + pb2) + (pc2 + pd2);
            float u3 = (pa3 + pb3) + (pc3 + pd3);
            u0 += __shfl_xor(u0, 16, 64); u0 += __shfl_xor(u0, 32, 64);
            u1 += __shfl_xor(u1, 16, 64); u1 += __shfl_xor(u1, 32, 64);
            u2 += __shfl_xor(u2, 16, 64); u2 += __shfl_xor(u2, 32, 64);
            u3 += __shfl_xor(u3, 16, 64); u3 += __shfl_xor(u3, 32, 64);
            t0 = fmaf(u0, inv, t0); t1 = fmaf(u1, inv, t1);
            t2 = fmaf(u2, inv, t2); t3 = fmaf(u3, inv, t3);
        }
        if (lane < 16) {
            float4 o4; o4.x = t0; o4.y = t1; o4.z = t2; o4.w = t3;
            *reinterpret_cast<float4*>(out + (size_t)n * 64 + cid * 4) = o4;
        }
    }
}

// ---------------------------------------------------------------------------
// p-list SpMM gather (touches only hp16); accumulates into out (RMW).
__global__ __launch_bounds__(256) void k_gp(
    const int* __restrict__ poff,
    const unsigned short* __restrict__ c16, const unsigned short* __restrict__ v16,
    const unsigned short* __restrict__ hp16, float* __restrict__ out)
{
    int lane = threadIdx.x & 63;
    int grp  = lane >> 4;
    int cid  = lane & 15;
    int wid  = blockIdx.x * (blockDim.x >> 6) + (threadIdx.x >> 6);
    int nw   = gridDim.x * (blockDim.x >> 6);
    for (int n = wid; n < NN; n += nw) {
        int word = poff[2 * NN + n];
        int b = word >> 8, deg = word & 255;
        float pa0 = 0.f, pa1 = 0.f, pa2 = 0.f, pa3 = 0.f;
        float pb0 = 0.f, pb1 = 0.f, pb2 = 0.f, pb3 = 0.f;
        float pc0 = 0.f, pc1 = 0.f, pc2 = 0.f, pc3 = 0.f;
        float pd0 = 0.f, pd1 = 0.f, pd2 = 0.f, pd3 = 0.f;
        int e = b + deg;
        for (int cb = b; cb < e; cb += 64) {
            int j  = cb + lane;
            int jc = min(j, e - 1);
            int cl = (int)c16[jc];
            float vl = (j < e) ? bf2f(v16[jc]) : 0.f;
            int c64 = min(64, e - cb);
            for (int k = 0; k < c64; k += 16) {
                int i0 = k + grp, i1 = k + 4 + grp;
                int i2 = k + 8 + grp, i3 = k + 12 + grp;
                int   s0 = __shfl(cl, i0, 64), s1 = __shfl(cl, i1, 64);
                int   s2 = __shfl(cl, i2, 64), s3 = __shfl(cl, i3, 64);
                float w0 = __shfl(vl, i0, 64), w1 = __shfl(vl, i1, 64);
                float w2 = __shfl(vl, i2, 64), w3 = __shfl(vl, i3, 64);
                uint2 r0 = *reinterpret_cast<const uint2*>(hp16 + (size_t)s0 * 64 + cid * 4);
                uint2 r1 = *reinterpret_cast<const uint2*>(hp16 + (size_t)s1 * 64 + cid * 4);
                uint2 r2 = *reinterpret_cast<const uint2*>(hp16 + (size_t)s2 * 64 + cid * 4);
                uint2 r3 = *reinterpret_cast<const uint2*>(hp16 + (size_t)s3 * 64 + cid * 4);
                pa0 = fmaf(w0, __uint_as_float(r0.x << 16), pa0);
                pa1 = fmaf(w0, __uint_as_float(r0.x & 0xFFFF0000u), pa1);
                pa2 = fmaf(w0, __uint_as_float(r0.y << 16), pa2);
                pa3 = fmaf(w0, __uint_as_float(r0.y & 0xFFFF0000u), pa3);
                pb0 = fmaf(w1, __uint_as_float(r1.x << 16), pb0);
                pb1 = fmaf(w1, __uint_as_float(r1.x & 0xFFFF0000u), pb1);
                pb2 = fmaf(w1, __uint_as_float(r1.y << 16), pb2);
                pb3 = fmaf(w1, __uint_as_float(r1.y & 0xFFFF0000u), pb3);
                pc0 = fmaf(w2, __uint_as_float(r2.x << 16), pc0);
                pc1 = fmaf(w2, __uint_as_float(r2.x & 0xFFFF0000u), pc1);
                pc2 = fmaf(w2, __uint_as_float(r2.y << 16), pc2);
                pc3 = fmaf(w2, __uint_as_float(r2.y & 0xFFFF0000u), pc3);
                pd0 = fmaf(w3, __uint_as_float(r3.x << 16), pd0);
                pd1 = fmaf(w3, __uint_as_float(r3.x & 0xFFFF0000u), pd1);
                pd2 = fmaf(w3, __uint_as_float(r3.y << 16), pd2);
                pd3 = fmaf(w3, __uint_as_float(r3.y & 0xFFFF0000u), pd3);
            }
        }
        float u0 = (pa0 + pb0) + (pc0 + pd0);
        float u1 = (pa1 + pb1) + (pc1 + pd1);
        float u2 = (pa2 + pb2) + (pc2 + pd2);
        float u3 = (pa3 + pb3) + (pc3 + pd3);
        u0 += __shfl_xor(u0, 16, 64); u0 += __shfl_xor(u0, 32, 64);
        u1 += __shfl_xor(u1, 16, 64); u1 += __shfl_xor(u1, 32, 64);
        u2 += __shfl_xor(u2, 16, 64); u2 += __shfl_xor(u2, 32, 64);
        u3 += __shfl_xor(u3, 16, 64); u3 += __shfl_xor(u3, 32, 64);
        if (lane < 16) {
            float4 o4 = *reinterpret_cast<float4*>(out + (size_t)n * 64 + cid * 4);
            o4.x += u0; o4.y += u1; o4.z += u2; o4.w += u3;
            *reinterpret_cast<float4*>(out + (size_t)n * 64 + cid * 4) = o4;
        }
    }
}

// ---------------------------------------------------------------------------
extern "C" void kernel_launch(void* const* d_in, const int* in_sizes, int n_in,
                              void* d_out, int out_size, void* d_ws, size_t ws_size,
                              hipStream_t stream)
{
    const float* feat = (const float*)d_in[0];
    const float* Wg   = (const float*)d_in[1];
    const float* bg   = (const float*)d_in[2];
    const float* as_  = (const float*)d_in[3];
    const float* ad_  = (const float*)d_in[4];
    const float* Wp   = (const float*)d_in[5];
    const float* bp   = (const float*)d_in[6];
    const float* pv   = (const float*)d_in[7];
    const int*   lu   = (const int*)d_in[8];
    const int*   ld   = (const int*)d_in[9];
    const int*   pi   = (const int*)d_in[10];
    float* out = (float*)d_out;

    unsigned short* h16  = (unsigned short*)d_ws;        // NN*64 ushort
    unsigned short* hp16 = h16 + (size_t)NN * 64;        // NN*64 ushort
    float* fbase = (float*)(hp16 + (size_t)NN * 64);
    float* ssrc  = fbase;                                // NN
    float* sdst  = ssrc + NN;                            // NN
    int*   poff  = (int*)(sdst + NN);                    // 3*NN packed (start<<8|deg)
    int*   cnt   = poff + 3 * NN;                        // 3*NBK*16 (64B-padded)
    unsigned* bglu = (unsigned*)(cnt + 3 * NBK * 16);    // NBK*CAPB
    unsigned* bgld = bglu + (size_t)NBK * CAPB;          // NBK*CAPB
    unsigned* bgpc = bgld + (size_t)NBK * CAPB;          // NBK*CAPB
    unsigned short* bgpv  = (unsigned short*)(bgpc + (size_t)NBK * CAPB); // NBK*CAPB us
    unsigned short* s_lu16 = bgpv + (size_t)NBK * CAPB;  // NBK*CAPB ushort
    unsigned short* s_ld16 = s_lu16 + (size_t)NBK * CAPB;
    unsigned short* c16    = s_ld16 + (size_t)NBK * CAPB;
    unsigned short* v16    = c16 + (size_t)NBK * CAPB;

    hipLaunchKernelGGL(k_gemm, dim3(2048), dim3(256), 0, stream,
                       feat, Wg, bg, as_, ad_, Wp, bp, h16, hp16, ssrc, sdst, cnt);
    hipLaunchKernelGGL(k_bin, dim3(3 * NT), dim3(256), 0, stream,
                       lu, ld, pi, pv, cnt, bglu, bgld, bgpc, bgpv);
    hipLaunchKernelGGL(k_b2c, dim3(3 * NBK), dim3(256), 0, stream,
                       cnt, bglu, bgld, bgpc, bgpv, s_lu16, s_ld16, c16, v16, poff);
    hipLaunchKernelGGL(k_ggat, dim3(2048), dim3(256), 0, stream,
                       poff, s_lu16, s_ld16, ssrc, sdst, h16, out);
    hipLaunchKernelGGL(k_gp, dim3(2048), dim3(256), 0, stream,
                       poff, c16, v16, hp16, out);
}

// Round 14
// 203.674 us; speedup vs baseline: 1.2499x; 1.0583x over previous
//
#include <hip/hip_runtime.h>
#include <cfloat>

#define NN 50000
#define EE 1600000
#define NEG 0.2f
#define BSH 7
#define BSZ 128                       // nodes per bucket
#define NBK ((NN + BSZ - 1) / BSZ)    // 391
#define CAPB 4608                     // fixed bucket capacity (mean 4096 + 8 sigma)
#define TSZ 8192                      // k_bin tile size (edges)
#define NT  ((EE + TSZ - 1) / TSZ)    // 196 tiles per list

__device__ inline float leaky(float v) { return v >= 0.f ? v : NEG * v; }

__device__ inline unsigned short f2bf(float f) {
    unsigned u = __float_as_uint(f);
    u += 0x7FFFu + ((u >> 16) & 1u);          // round-to-nearest-even
    return (unsigned short)(u >> 16);
}
__device__ inline float bf2f(unsigned short s) {
    return __uint_as_float(((unsigned)s) << 16);
}

// ---------------------------------------------------------------------------
// GEMM: h16 = bf16(feat@Wg+bg) ; hp16 = bf16(feat@Wp+bp) ; ssrc/sdst f32.
// Also zeroes the bucket cursor array.
__global__ __launch_bounds__(256) void k_gemm(
    const float* __restrict__ feat, const float* __restrict__ Wg,
    const float* __restrict__ bg, const float* __restrict__ as_,
    const float* __restrict__ ad_, const float* __restrict__ Wp,
    const float* __restrict__ bp,
    unsigned short* __restrict__ h16, unsigned short* __restrict__ hp16,
    float* __restrict__ ssrc, float* __restrict__ sdst,
    int* __restrict__ cnt)
{
    __shared__ float sWg[64 * 64];
    __shared__ float sWp[64 * 64];
    __shared__ float sb[4 * 64];
    int t = threadIdx.x;
    int gid = blockIdx.x * 256 + t;
    if (gid < 3 * NBK * 16) cnt[gid] = 0;
    for (int i = t; i < 4096; i += 256) { sWg[i] = Wg[i]; sWp[i] = Wp[i]; }
    if (t < 64)       sb[t] = bg[t];
    else if (t < 128) sb[t] = bp[t - 64];
    else if (t < 192) sb[t] = as_[t - 128];
    else              sb[t] = ad_[t - 192];
    __syncthreads();

    int lane = t & 63;
    int w    = t >> 6;
    int nw   = (gridDim.x * blockDim.x) >> 6;
    for (int n = blockIdx.x * 4 + w; n < NN; n += nw) {
        float fv   = feat[n * 64 + lane];
        float accg = sb[lane];
        float accp = sb[64 + lane];
#pragma unroll
        for (int k = 0; k < 64; ++k) {
            float f = __shfl(fv, k, 64);
            accg = fmaf(f, sWg[k * 64 + lane], accg);
            accp = fmaf(f, sWp[k * 64 + lane], accp);
        }
        h16 [n * 64 + lane] = f2bf(accg);
        hp16[n * 64 + lane] = f2bf(accp);
        float vs = accg * sb[128 + lane];
        float vd = accg * sb[192 + lane];
#pragma unroll
        for (int off = 32; off > 0; off >>= 1) {
            vs += __shfl_xor(vs, off, 64);
            vd += __shfl_xor(vd, off, 64);
        }
        if (lane == 0) { ssrc[n] = vs; sdst[n] = vd; }
    }
}

// ---------------------------------------------------------------------------
// tile-local bucket sort + chunk reservation into fixed-capacity regions.
// 512 threads: halves per-phase sweep length, doubles resident waves.
__global__ __launch_bounds__(512) void k_bin(
    const int* __restrict__ lu, const int* __restrict__ ld,
    const int* __restrict__ pi, const float* __restrict__ pv,
    int* __restrict__ cnt,
    unsigned* __restrict__ bglu, unsigned* __restrict__ bgld,
    unsigned* __restrict__ bgpc, unsigned short* __restrict__ bgpv)
{
    __shared__ int hist[NBK];
    __shared__ int loff[NBK];
    __shared__ int gbase[NBK];
    __shared__ int part[512];
    __shared__ unsigned stage[TSZ];
    int t = threadIdx.x;
    int task = blockIdx.x;
    int list = task / NT, tile = task - list * NT;
    int e0 = tile * TSZ, e1 = min(e0 + TSZ, EE), sz = e1 - e0;
    const int* srcp; const int* dstp;
    if (list == 0)      { srcp = lu;      dstp = lu + EE; }
    else if (list == 1) { srcp = ld;      dstp = ld + EE; }
    else                { srcp = pi + EE; dstp = pi; }
    for (int i = t; i < NBK; i += 512) hist[i] = 0;
    __syncthreads();
    for (int i = t; i < sz; i += 512)
        atomicAdd(&hist[dstp[e0 + i] >> BSH], 1);
    __syncthreads();
    {
        // scan over NBK buckets: one bucket per thread (NBK=391 < 512)
        int s = (t < NBK) ? hist[t] : 0;
        part[t] = s;
        __syncthreads();
        for (int d = 1; d < 512; d <<= 1) {
            int v = 0;
            if (t >= d) v = part[t - d];
            __syncthreads();
            if (t >= d) part[t] += v;
            __syncthreads();
        }
        if (t < NBK) loff[t] = part[t] - s;    // exclusive
    }
    __syncthreads();
    for (int i = t; i < NBK; i += 512) {
        int c = hist[i];
        if (c) {
            int pos = atomicAdd(&cnt[(list * NBK + i) * 16], c);
            gbase[i] = i * CAPB + pos;
        }
        hist[i] = loff[i];
    }
    __syncthreads();
    if (list == 2) {
        for (int i = t; i < sz; i += 512) {
            int d = dstp[e0 + i];
            unsigned pay = (unsigned)i | ((unsigned)d << 16);
            int r = atomicAdd(&hist[d >> BSH], 1);
            stage[r] = pay;
        }
        __syncthreads();
        for (int i = t; i < sz; i += 512) {
            unsigned v = stage[i];
            int b = (int)(v >> (16 + BSH));
            int li = (int)(v & 0xFFFFu);
            int addr = gbase[b] + (i - loff[b]);
            bgpc[addr] = (unsigned)srcp[e0 + li] | (v & 0xFFFF0000u);
            bgpv[addr] = f2bf(pv[e0 + li]);
        }
    } else {
        for (int i = t; i < sz; i += 512) {
            int d = dstp[e0 + i];
            unsigned pay = (unsigned)srcp[e0 + i] | ((unsigned)d << 16);
            int r = atomicAdd(&hist[d >> BSH], 1);
            stage[r] = pay;
        }
        __syncthreads();
        unsigned* arr = list ? bgld : bglu;
        for (int i = t; i < sz; i += 512) {
            unsigned v = stage[i];
            int b = (int)(v >> (16 + BSH));
            arr[gbase[b] + (i - loff[b])] = v;
        }
    }
}

// ---------------------------------------------------------------------------
// per-(list,bucket): refine bucket region to per-node CSR; emits packed
// poff = (region_start<<8)|deg and compact ushort payload arrays. 512 thr.
__global__ __launch_bounds__(512) void k_b2c(
    const int* __restrict__ cnt,
    const unsigned* __restrict__ bglu, const unsigned* __restrict__ bgld,
    const unsigned* __restrict__ bgpc, const unsigned short* __restrict__ bgpv,
    unsigned short* __restrict__ s_lu16, unsigned short* __restrict__ s_ld16,
    unsigned short* __restrict__ c16, unsigned short* __restrict__ v16,
    int* __restrict__ poff)
{
    __shared__ int ecnt[BSZ];
    __shared__ int scn[BSZ];
    __shared__ unsigned buf[CAPB];
    __shared__ unsigned short bufv[CAPB];
    int bid  = blockIdx.x;
    int list = bid / NBK, b = bid - list * NBK;
    int size = min(cnt[(list * NBK + b) * 16], CAPB);
    int base = b * CAPB;
    int t = threadIdx.x;
    if (t < BSZ) ecnt[t] = 0;
    __syncthreads();
    const unsigned* arr = (list == 0) ? bglu : (list == 1) ? bgld : bgpc;
    for (int i = t; i < size; i += 512) {
        unsigned v = arr[base + i];
        buf[i] = v;
        if (list == 2) bufv[i] = bgpv[base + i];
        atomicAdd(&ecnt[(v >> 16) & (BSZ - 1)], 1);
    }
    __syncthreads();
    if (t < BSZ) scn[t] = ecnt[t];
    __syncthreads();
    for (int d = 1; d < BSZ; d <<= 1) {
        int add = 0;
        if (t < BSZ && t >= d) add = scn[t - d];
        __syncthreads();
        if (t < BSZ && t >= d) scn[t] += add;
        __syncthreads();
    }
    int n0 = b << BSH;
    if (t < BSZ) {
        int deg  = ecnt[t];
        int excl = scn[t] - deg;
        if (n0 + t < NN)
            poff[list * NN + n0 + t] = ((base + excl) << 8) | deg;
    }
    __syncthreads();
    if (t < BSZ) ecnt[t] = scn[t] - ecnt[t];     // cursors
    __syncthreads();
    if (list == 2) {
        for (int i = t; i < size; i += 512) {
            unsigned v = buf[i];
            int pos = atomicAdd(&ecnt[(v >> 16) & (BSZ - 1)], 1);
            c16[base + pos] = (unsigned short)(v & 0xFFFFu);
            v16[base + pos] = bufv[i];
        }
    } else {
        unsigned short* o16 = list ? s_ld16 : s_lu16;
        for (int i = t; i < size; i += 512) {
            unsigned v = buf[i];
            int pos = atomicAdd(&ecnt[(v >> 16) & (BSZ - 1)], 1);
            o16[base + pos] = (unsigned short)(v & 0xFFFFu);
        }
    }
}

// ---------------------------------------------------------------------------
// GAT gather (lu+ld only; touches only h16 -> halved L2 working set).
// One wave per node; 16 edges per iteration via 4 independent uint2 loads;
// tail via clamped index + zero weight (no tail loop).
__global__ __launch_bounds__(256) void k_ggat(
    const int* __restrict__ poff,
    const unsigned short* __restrict__ s_lu16, const unsigned short* __restrict__ s_ld16,
    const float* __restrict__ ssrc, const float* __restrict__ sdst,
    const unsigned short* __restrict__ h16, float* __restrict__ out)
{
    int lane = threadIdx.x & 63;
    int grp  = lane >> 4;            // edge subgroup 0..3
    int cid  = lane & 15;            // channel-quad id
    int wid  = blockIdx.x * (blockDim.x >> 6) + (threadIdx.x >> 6);
    int nw   = gridDim.x * (blockDim.x >> 6);
    for (int n = wid; n < NN; n += nw) {
        float sd = sdst[n];
        float t0 = 0.f, t1 = 0.f, t2 = 0.f, t3 = 0.f;
        for (int list = 0; list < 2; ++list) {
            const unsigned short* ss = list ? s_ld16 : s_lu16;
            int word = poff[list * NN + n];
            int b = word >> 8, deg = word & 255;
            if (deg <= 0) continue;
            int e = b + deg;
            float pa0 = 0.f, pa1 = 0.f, pa2 = 0.f, pa3 = 0.f;
            float pb0 = 0.f, pb1 = 0.f, pb2 = 0.f, pb3 = 0.f;
            float pc0 = 0.f, pc1 = 0.f, pc2 = 0.f, pc3 = 0.f;
            float pd0 = 0.f, pd1 = 0.f, pd2 = 0.f, pd3 = 0.f, den = 0.f;
            for (int cb = b; cb < e; cb += 64) {
                int j  = cb + lane;
                int jc = min(j, e - 1);
                int sl = (int)ss[jc];
                float ex = 0.f;
                if (j < e) { ex = __expf(leaky(ssrc[sl] + sd)); den += ex; }
                int c64 = min(64, e - cb);
                for (int k = 0; k < c64; k += 16) {
                    int i0 = k + grp, i1 = k + 4 + grp;
                    int i2 = k + 8 + grp, i3 = k + 12 + grp;
                    int   s0 = __shfl(sl, i0, 64), s1 = __shfl(sl, i1, 64);
                    int   s2 = __shfl(sl, i2, 64), s3 = __shfl(sl, i3, 64);
                    float w0 = __shfl(ex, i0, 64), w1 = __shfl(ex, i1, 64);
                    float w2 = __shfl(ex, i2, 64), w3 = __shfl(ex, i3, 64);
                    uint2 r0 = *reinterpret_cast<const uint2*>(h16 + (size_t)s0 * 64 + cid * 4);
                    uint2 r1 = *reinterpret_cast<const uint2*>(h16 + (size_t)s1 * 64 + cid * 4);
                    uint2 r2 = *reinterpret_cast<const uint2*>(h16 + (size_t)s2 * 64 + cid * 4);
                    uint2 r3 = *reinterpret_cast<const uint2*>(h16 + (size_t)s3 * 64 + cid * 4);
                    pa0 = fmaf(w0, __uint_as_float(r0.x << 16), pa0);
                    pa1 = fmaf(w0, __uint_as_float(r0.x & 0xFFFF0000u), pa1);
                    pa2 = fmaf(w0, __uint_as_float(r0.y << 16), pa2);
                    pa3 = fmaf(w0, __uint_as_float(r0.y & 0xFFFF0000u), pa3);
                    pb0 = fmaf(w1, __uint_as_float(r1.x << 16), pb0);
                    pb1 = fmaf(w1, __uint_as_float(r1.x & 0xFFFF0000u), pb1);
                    pb2 = fmaf(w1, __uint_as_float(r1.y << 16), pb2);
                    pb3 = fmaf(w1, __uint_as_float(r1.y & 0xFFFF0000u), pb3);
                    pc0 = fmaf(w2, __uint_as_float(r2.x << 16), pc0);
                    pc1 = fmaf(w2, __uint_as_float(r2.x & 0xFFFF0000u), pc1);
                    pc2 = fmaf(w2, __uint_as_float(r2.y << 16), pc2);
                    pc3 = fmaf(w2, __uint_as_float(r2.y & 0xFFFF0000u), pc3);
                    pd0 = fmaf(w3, __uint_as_float(r3.x << 16), pd0);
                    pd1 = fmaf(w3, __uint_as_float(r3.x & 0xFFFF0000u), pd1);
                    pd2 = fmaf(w3, __uint_as_float(r3.y << 16), pd2);
                    pd3 = fmaf(w3, __uint_as_float(r3.y & 0xFFFF0000u), pd3);
                }
            }
#pragma unroll
            for (int o = 32; o; o >>= 1) den += __shfl_xor(den, o, 64);
            float inv = 1.f / (den + 1e-16f);
            float u0 = (pa0 + pb0) + (pc0 + pd0);
            float u1 = (pa1 + pb1) + (pc1 + pd1);
            float u2 = (pa2 + pb2) + (pc2 + pd2);
            float u3 = (pa3 + pb3) + (pc3 + pd3);
            u0 += __shfl_xor(u0, 16, 64); u0 += __shfl_xor(u0, 32, 64);
            u1 += __shfl_xor(u1, 16, 64); u1 += __shfl_xor(u1, 32, 64);
            u2 += __shfl_xor(u2, 16, 64); u2 += __shfl_xor(u2, 32, 64);
            u3 += __shfl_xor(u3, 16, 64); u3 += __shfl_xor(u3, 32, 64);
            t0 = fmaf(u0, inv, t0); t1 = fmaf(u1, inv, t1);
            t2 = fmaf(u2, inv, t2); t3 = fmaf(u3, inv, t3);
        }
        if (lane < 16) {
            float4 o4; o4.x = t0; o4.y = t1; o4.z = t2; o4.w = t3;
            *reinterpret_cast<float4*>(out + (size_t)n * 64 + cid * 4) = o4;
        }
    }
}

// ---------------------------------------------------------------------------
// p-list SpMM gather (touches only hp16); accumulates into out (RMW).
__global__ __launch_bounds__(256) void k_gp(
    const int* __restrict__ poff,
    const unsigned short* __restrict__ c16, const unsigned short* __restrict__ v16,
    const unsigned short* __restrict__ hp16, float* __restrict__ out)
{
    int lane = threadIdx.x & 63;
    int grp  = lane >> 4;
    int cid  = lane & 15;
    int wid  = blockIdx.x * (blockDim.x >> 6) + (threadIdx.x >> 6);
    int nw   = gridDim.x * (blockDim.x >> 6);
    for (int n = wid; n < NN; n += nw) {
        int word = poff[2 * NN + n];
        int b = word >> 8, deg = word & 255;
        float pa0 = 0.f, pa1 = 0.f, pa2 = 0.f, pa3 = 0.f;
        float pb0 = 0.f, pb1 = 0.f, pb2 = 0.f, pb3 = 0.f;
        float pc0 = 0.f, pc1 = 0.f, pc2 = 0.f, pc3 = 0.f;
        float pd0 = 0.f, pd1 = 0.f, pd2 = 0.f, pd3 = 0.f;
        int e = b + deg;
        for (int cb = b; cb < e; cb += 64) {
            int j  = cb + lane;
            int jc = min(j, e - 1);
            int cl = (int)c16[jc];
            float vl = (j < e) ? bf2f(v16[jc]) : 0.f;
            int c64 = min(64, e - cb);
            for (int k = 0; k < c64; k += 16) {
                int i0 = k + grp, i1 = k + 4 + grp;
                int i2 = k + 8 + grp, i3 = k + 12 + grp;
                int   s0 = __shfl(cl, i0, 64), s1 = __shfl(cl, i1, 64);
                int   s2 = __shfl(cl, i2, 64), s3 = __shfl(cl, i3, 64);
                float w0 = __shfl(vl, i0, 64), w1 = __shfl(vl, i1, 64);
                float w2 = __shfl(vl, i2, 64), w3 = __shfl(vl, i3, 64);
                uint2 r0 = *reinterpret_cast<const uint2*>(hp16 + (size_t)s0 * 64 + cid * 4);
                uint2 r1 = *reinterpret_cast<const uint2*>(hp16 + (size_t)s1 * 64 + cid * 4);
                uint2 r2 = *reinterpret_cast<const uint2*>(hp16 + (size_t)s2 * 64 + cid * 4);
                uint2 r3 = *reinterpret_cast<const uint2*>(hp16 + (size_t)s3 * 64 + cid * 4);
                pa0 = fmaf(w0, __uint_as_float(r0.x << 16), pa0);
                pa1 = fmaf(w0, __uint_as_float(r0.x & 0xFFFF0000u), pa1);
                pa2 = fmaf(w0, __uint_as_float(r0.y << 16), pa2);
                pa3 = fmaf(w0, __uint_as_float(r0.y & 0xFFFF0000u), pa3);
                pb0 = fmaf(w1, __uint_as_float(r1.x << 16), pb0);
                pb1 = fmaf(w1, __uint_as_float(r1.x & 0xFFFF0000u), pb1);
                pb2 = fmaf(w1, __uint_as_float(r1.y << 16), pb2);
                pb3 = fmaf(w1, __uint_as_float(r1.y & 0xFFFF0000u), pb3);
                pc0 = fmaf(w2, __uint_as_float(r2.x << 16), pc0);
                pc1 = fmaf(w2, __uint_as_float(r2.x & 0xFFFF0000u), pc1);
                pc2 = fmaf(w2, __uint_as_float(r2.y << 16), pc2);
                pc3 = fmaf(w2, __uint_as_float(r2.y & 0xFFFF0000u), pc3);
                pd0 = fmaf(w3, __uint_as_float(r3.x << 16), pd0);
                pd1 = fmaf(w3, __uint_as_float(r3.x & 0xFFFF0000u), pd1);
                pd2 = fmaf(w3, __uint_as_float(r3.y << 16), pd2);
                pd3 = fmaf(w3, __uint_as_float(r3.y & 0xFFFF0000u), pd3);
            }
        }
        float u0 = (pa0 + pb0) + (pc0 + pd0);
        float u1 = (pa1 + pb1) + (pc1 + pd1);
        float u2 = (pa2 + pb2) + (pc2 + pd2);
        float u3 = (pa3 + pb3) + (pc3 + pd3);
        u0 += __shfl_xor(u0, 16, 64); u0 += __shfl_xor(u0, 32, 64);
        u1 += __shfl_xor(u1, 16, 64); u1 += __shfl_xor(u1, 32, 64);
        u2 += __shfl_xor(u2, 16, 64); u2 += __shfl_xor(u2, 32, 64);
        u3 += __shfl_xor(u3, 16, 64); u3 += __shfl_xor(u3, 32, 64);
        if (lane < 16) {
            float4 o4 = *reinterpret_cast<float4*>(out + (size_t)n * 64 + cid * 4);
            o4.x += u0; o4.y += u1; o4.z += u2; o4.w += u3;
            *reinterpret_cast<float4*>(out + (size_t)n * 64 + cid * 4) = o4;
        }
    }
}

// ---------------------------------------------------------------------------
extern "C" void kernel_launch(void* const* d_in, const int* in_sizes, int n_in,
                              void* d_out, int out_size, void* d_ws, size_t ws_size,
                              hipStream_t stream)
{
    const float* feat = (const float*)d_in[0];
    const float* Wg   = (const float*)d_in[1];
    const float* bg   = (const float*)d_in[2];
    const float* as_  = (const float*)d_in[3];
    const float* ad_  = (const float*)d_in[4];
    const float* Wp   = (const float*)d_in[5];
    const float* bp   = (const float*)d_in[6];
    const float* pv   = (const float*)d_in[7];
    const int*   lu   = (const int*)d_in[8];
    const int*   ld   = (const int*)d_in[9];
    const int*   pi   = (const int*)d_in[10];
    float* out = (float*)d_out;

    unsigned short* h16  = (unsigned short*)d_ws;        // NN*64 ushort
    unsigned short* hp16 = h16 + (size_t)NN * 64;        // NN*64 ushort
    float* fbase = (float*)(hp16 + (size_t)NN * 64);
    float* ssrc  = fbase;                                // NN
    float* sdst  = ssrc + NN;                            // NN
    int*   poff  = (int*)(sdst + NN);                    // 3*NN packed (start<<8|deg)
    int*   cnt   = poff + 3 * NN;                        // 3*NBK*16 (64B-padded)
    unsigned* bglu = (unsigned*)(cnt + 3 * NBK * 16);    // NBK*CAPB
    unsigned* bgld = bglu + (size_t)NBK * CAPB;          // NBK*CAPB
    unsigned* bgpc = bgld + (size_t)NBK * CAPB;          // NBK*CAPB
    unsigned short* bgpv  = (unsigned short*)(bgpc + (size_t)NBK * CAPB); // NBK*CAPB us
    unsigned short* s_lu16 = bgpv + (size_t)NBK * CAPB;  // NBK*CAPB ushort
    unsigned short* s_ld16 = s_lu16 + (size_t)NBK * CAPB;
    unsigned short* c16    = s_ld16 + (size_t)NBK * CAPB;
    unsigned short* v16    = c16 + (size_t)NBK * CAPB;

    hipLaunchKernelGGL(k_gemm, dim3(2048), dim3(256), 0, stream,
                       feat, Wg, bg, as_, ad_, Wp, bp, h16, hp16, ssrc, sdst, cnt);
    hipLaunchKernelGGL(k_bin, dim3(3 * NT), dim3(512), 0, stream,
                       lu, ld, pi, pv, cnt, bglu, bgld, bgpc, bgpv);
    hipLaunchKernelGGL(k_b2c, dim3(3 * NBK), dim3(512), 0, stream,
                       cnt, bglu, bgld, bgpc, bgpv, s_lu16, s_ld16, c16, v16, poff);
    hipLaunchKernelGGL(k_ggat, dim3(2048), dim3(256), 0, stream,
                       poff, s_lu16, s_ld16, ssrc, sdst, h16, out);
    hipLaunchKernelGGL(k_gp, dim3(2048), dim3(256), 0, stream,
                       poff, c16, v16, hp16, out);
}

// Round 15
// 172.373 us; speedup vs baseline: 1.4769x; 1.1816x over previous
//
#include <hip/hip_runtime.h>
#include <cfloat>

#define NN 50000
#define EE 1600000
#define NEG 0.2f
#define BSH 7
#define BSZ 128                       // nodes per bucket
#define NBK ((NN + BSZ - 1) / BSZ)    // 391
#define CAPB 4608                     // fixed bucket capacity (mean 4096 + 8 sigma)
#define TSZ 8192                      // k_bin tile size (edges)
#define NT  ((EE + TSZ - 1) / TSZ)    // 196 tiles per list

typedef __attribute__((ext_vector_type(8))) short short8;
typedef __attribute__((ext_vector_type(4))) float f32x4;

__device__ inline float leaky(float v) { return v >= 0.f ? v : NEG * v; }

__device__ inline unsigned short f2bf(float f) {
    unsigned u = __float_as_uint(f);
    u += 0x7FFFu + ((u >> 16) & 1u);          // round-to-nearest-even
    return (unsigned short)(u >> 16);
}
__device__ inline float bf2f(unsigned short s) {
    return __uint_as_float(((unsigned)s) << 16);
}

// ---------------------------------------------------------------------------
// MFMA GEMM: h16 = bf16(feat@Wg+bg) ; hp16 = bf16(feat@Wp+bp) ; ssrc/sdst f32.
// 16-row tiles (50000 = 16*3125 exactly), one wave per tile, 16 MFMA/tile.
// A: lane l -> feat[n0+(l&15)][(l>>4)*8+j]; B: from bf16 W^T in LDS (b128);
// D: row=(l>>4)*4+r, col=l&15 (m89-verified). Also zeroes cnt.
__global__ __launch_bounds__(256) void k_gemm(
    const float* __restrict__ feat, const float* __restrict__ Wg,
    const float* __restrict__ bg, const float* __restrict__ as_,
    const float* __restrict__ ad_, const float* __restrict__ Wp,
    const float* __restrict__ bp,
    unsigned short* __restrict__ h16, unsigned short* __restrict__ hp16,
    float* __restrict__ ssrc, float* __restrict__ sdst,
    int* __restrict__ cnt)
{
    __shared__ unsigned short sWgT[64 * 64];   // [o][k] bf16
    __shared__ unsigned short sWpT[64 * 64];
    int t = threadIdx.x;
    int gid = blockIdx.x * 256 + t;
    if (gid < 3 * NBK * 16) cnt[gid] = 0;
    for (int i = t; i < 4096; i += 256) {
        int k = i >> 6, o = i & 63;            // W[k][o] -> WT[o][k]
        sWgT[o * 64 + k] = f2bf(Wg[i]);
        sWpT[o * 64 + k] = f2bf(Wp[i]);
    }
    __syncthreads();

    int lane = t & 63, w = t >> 6;
    int tile = blockIdx.x * 4 + w;
    if (tile >= NN / 16) return;
    int n0 = tile * 16;
    int m = lane & 15, g = lane >> 4;          // m = row-in-tile / col; g = quad
    // --- A fragments (k 0..31 and 32..63) ---
    const float* frow = feat + (size_t)(n0 + m) * 64 + g * 8;
    float4 fa = *reinterpret_cast<const float4*>(frow);
    float4 fb = *reinterpret_cast<const float4*>(frow + 4);
    float4 fc = *reinterpret_cast<const float4*>(frow + 32);
    float4 fd = *reinterpret_cast<const float4*>(frow + 36);
    short8 a0, a1;
    a0[0]=(short)f2bf(fa.x); a0[1]=(short)f2bf(fa.y); a0[2]=(short)f2bf(fa.z); a0[3]=(short)f2bf(fa.w);
    a0[4]=(short)f2bf(fb.x); a0[5]=(short)f2bf(fb.y); a0[6]=(short)f2bf(fb.z); a0[7]=(short)f2bf(fb.w);
    a1[0]=(short)f2bf(fc.x); a1[1]=(short)f2bf(fc.y); a1[2]=(short)f2bf(fc.z); a1[3]=(short)f2bf(fc.w);
    a1[4]=(short)f2bf(fd.x); a1[5]=(short)f2bf(fd.y); a1[6]=(short)f2bf(fd.z); a1[7]=(short)f2bf(fd.w);

    f32x4 accg[4], accp[4];
#pragma unroll
    for (int tc = 0; tc < 4; ++tc) {
        const unsigned short* bgp = &sWgT[(16 * tc + m) * 64 + g * 8];
        short8 b0 = *reinterpret_cast<const short8*>(bgp);
        short8 b1 = *reinterpret_cast<const short8*>(bgp + 32);
        f32x4 c = {0.f, 0.f, 0.f, 0.f};
        c = __builtin_amdgcn_mfma_f32_16x16x32_bf16(a0, b0, c, 0, 0, 0);
        c = __builtin_amdgcn_mfma_f32_16x16x32_bf16(a1, b1, c, 0, 0, 0);
        accg[tc] = c;
        const unsigned short* bpp = &sWpT[(16 * tc + m) * 64 + g * 8];
        short8 d0 = *reinterpret_cast<const short8*>(bpp);
        short8 d1 = *reinterpret_cast<const short8*>(bpp + 32);
        f32x4 e = {0.f, 0.f, 0.f, 0.f};
        e = __builtin_amdgcn_mfma_f32_16x16x32_bf16(a0, d0, e, 0, 0, 0);
        e = __builtin_amdgcn_mfma_f32_16x16x32_bf16(a1, d1, e, 0, 0, 0);
        accp[tc] = e;
    }
    // --- bias + stores + logits ---
    float bgv[4], bpv[4], asv[4], adv[4];
#pragma unroll
    for (int tc = 0; tc < 4; ++tc) {
        int col = 16 * tc + m;
        bgv[tc] = bg[col]; bpv[tc] = bp[col];
        asv[tc] = as_[col]; adv[tc] = ad_[col];
    }
    float ps[4] = {0.f,0.f,0.f,0.f}, pd[4] = {0.f,0.f,0.f,0.f};
#pragma unroll
    for (int tc = 0; tc < 4; ++tc) {
#pragma unroll
        for (int r = 0; r < 4; ++r) {
            float hv = accg[tc][r] + bgv[tc];
            int row = n0 + g * 4 + r;
            h16[(size_t)row * 64 + 16 * tc + m] = f2bf(hv);
            ps[r] = fmaf(hv, asv[tc], ps[r]);
            pd[r] = fmaf(hv, adv[tc], pd[r]);
            float pv2 = accp[tc][r] + bpv[tc];
            hp16[(size_t)row * 64 + 16 * tc + m] = f2bf(pv2);
        }
    }
#pragma unroll
    for (int o = 1; o < 16; o <<= 1) {
#pragma unroll
        for (int r = 0; r < 4; ++r) {
            ps[r] += __shfl_xor(ps[r], o, 64);
            pd[r] += __shfl_xor(pd[r], o, 64);
        }
    }
    if (m == 0) {
#pragma unroll
        for (int r = 0; r < 4; ++r) {
            ssrc[n0 + g * 4 + r] = ps[r];
            sdst[n0 + g * 4 + r] = pd[r];
        }
    }
}

// ---------------------------------------------------------------------------
// tile-local bucket sort + chunk reservation into fixed-capacity regions.
__global__ __launch_bounds__(512) void k_bin(
    const int* __restrict__ lu, const int* __restrict__ ld,
    const int* __restrict__ pi, const float* __restrict__ pv,
    int* __restrict__ cnt,
    unsigned* __restrict__ bglu, unsigned* __restrict__ bgld,
    unsigned* __restrict__ bgpc, unsigned short* __restrict__ bgpv)
{
    __shared__ int hist[NBK];
    __shared__ int loff[NBK];
    __shared__ int gbase[NBK];
    __shared__ int part[512];
    __shared__ unsigned stage[TSZ];
    int t = threadIdx.x;
    int task = blockIdx.x;
    int list = task / NT, tile = task - list * NT;
    int e0 = tile * TSZ, e1 = min(e0 + TSZ, EE), sz = e1 - e0;
    const int* srcp; const int* dstp;
    if (list == 0)      { srcp = lu;      dstp = lu + EE; }
    else if (list == 1) { srcp = ld;      dstp = ld + EE; }
    else                { srcp = pi + EE; dstp = pi; }
    for (int i = t; i < NBK; i += 512) hist[i] = 0;
    __syncthreads();
    for (int i = t; i < sz; i += 512)
        atomicAdd(&hist[dstp[e0 + i] >> BSH], 1);
    __syncthreads();
    {
        int s = (t < NBK) ? hist[t] : 0;
        part[t] = s;
        __syncthreads();
        for (int d = 1; d < 512; d <<= 1) {
            int v = 0;
            if (t >= d) v = part[t - d];
            __syncthreads();
            if (t >= d) part[t] += v;
            __syncthreads();
        }
        if (t < NBK) loff[t] = part[t] - s;    // exclusive
    }
    __syncthreads();
    for (int i = t; i < NBK; i += 512) {
        int c = hist[i];
        if (c) {
            int pos = atomicAdd(&cnt[(list * NBK + i) * 16], c);
            gbase[i] = i * CAPB + pos;
        }
        hist[i] = loff[i];
    }
    __syncthreads();
    if (list == 2) {
        for (int i = t; i < sz; i += 512) {
            int d = dstp[e0 + i];
            unsigned pay = (unsigned)i | ((unsigned)d << 16);
            int r = atomicAdd(&hist[d >> BSH], 1);
            stage[r] = pay;
        }
        __syncthreads();
        for (int i = t; i < sz; i += 512) {
            unsigned v = stage[i];
            int b = (int)(v >> (16 + BSH));
            int li = (int)(v & 0xFFFFu);
            int addr = gbase[b] + (i - loff[b]);
            bgpc[addr] = (unsigned)srcp[e0 + li] | (v & 0xFFFF0000u);
            bgpv[addr] = f2bf(pv[e0 + li]);
        }
    } else {
        for (int i = t; i < sz; i += 512) {
            int d = dstp[e0 + i];
            unsigned pay = (unsigned)srcp[e0 + i] | ((unsigned)d << 16);
            int r = atomicAdd(&hist[d >> BSH], 1);
            stage[r] = pay;
        }
        __syncthreads();
        unsigned* arr = list ? bgld : bglu;
        for (int i = t; i < sz; i += 512) {
            unsigned v = stage[i];
            int b = (int)(v >> (16 + BSH));
            arr[gbase[b] + (i - loff[b])] = v;
        }
    }
}

// ---------------------------------------------------------------------------
// per-(list,bucket): refine bucket region to per-node CSR; emits packed
// poff = (region_start<<8)|deg and compact ushort payload arrays.
__global__ __launch_bounds__(512) void k_b2c(
    const int* __restrict__ cnt,
    const unsigned* __restrict__ bglu, const unsigned* __restrict__ bgld,
    const unsigned* __restrict__ bgpc, const unsigned short* __restrict__ bgpv,
    unsigned short* __restrict__ s_lu16, unsigned short* __restrict__ s_ld16,
    unsigned short* __restrict__ c16, unsigned short* __restrict__ v16,
    int* __restrict__ poff)
{
    __shared__ int ecnt[BSZ];
    __shared__ int scn[BSZ];
    __shared__ unsigned buf[CAPB];
    __shared__ unsigned short bufv[CAPB];
    int bid  = blockIdx.x;
    int list = bid / NBK, b = bid - list * NBK;
    int size = min(cnt[(list * NBK + b) * 16], CAPB);
    int base = b * CAPB;
    int t = threadIdx.x;
    if (t < BSZ) ecnt[t] = 0;
    __syncthreads();
    const unsigned* arr = (list == 0) ? bglu : (list == 1) ? bgld : bgpc;
    for (int i = t; i < size; i += 512) {
        unsigned v = arr[base + i];
        buf[i] = v;
        if (list == 2) bufv[i] = bgpv[base + i];
        atomicAdd(&ecnt[(v >> 16) & (BSZ - 1)], 1);
    }
    __syncthreads();
    if (t < BSZ) scn[t] = ecnt[t];
    __syncthreads();
    for (int d = 1; d < BSZ; d <<= 1) {
        int add = 0;
        if (t < BSZ && t >= d) add = scn[t - d];
        __syncthreads();
        if (t < BSZ && t >= d) scn[t] += add;
        __syncthreads();
    }
    int n0 = b << BSH;
    if (t < BSZ) {
        int deg  = ecnt[t];
        int excl = scn[t] - deg;
        if (n0 + t < NN)
            poff[list * NN + n0 + t] = ((base + excl) << 8) | deg;
    }
    __syncthreads();
    if (t < BSZ) ecnt[t] = scn[t] - ecnt[t];     // cursors
    __syncthreads();
    if (list == 2) {
        for (int i = t; i < size; i += 512) {
            unsigned v = buf[i];
            int pos = atomicAdd(&ecnt[(v >> 16) & (BSZ - 1)], 1);
            c16[base + pos] = (unsigned short)(v & 0xFFFFu);
            v16[base + pos] = bufv[i];
        }
    } else {
        unsigned short* o16 = list ? s_ld16 : s_lu16;
        for (int i = t; i < size; i += 512) {
            unsigned v = buf[i];
            int pos = atomicAdd(&ecnt[(v >> 16) & (BSZ - 1)], 1);
            o16[base + pos] = (unsigned short)(v & 0xFFFFu);
        }
    }
}

// ---------------------------------------------------------------------------
// GAT gather (lu+ld only; touches only h16 -> halved L2 working set).
__global__ __launch_bounds__(256) void k_ggat(
    const int* __restrict__ poff,
    const unsigned short* __restrict__ s_lu16, const unsigned short* __restrict__ s_ld16,
    const float* __restrict__ ssrc, const float* __restrict__ sdst,
    const unsigned short* __restrict__ h16, float* __restrict__ out)
{
    int lane = threadIdx.x & 63;
    int grp  = lane >> 4;            // edge subgroup 0..3
    int cid  = lane & 15;            // channel-quad id
    int wid  = blockIdx.x * (blockDim.x >> 6) + (threadIdx.x >> 6);
    int nw   = gridDim.x * (blockDim.x >> 6);
    for (int n = wid; n < NN; n += nw) {
        float sd = sdst[n];
        float t0 = 0.f, t1 = 0.f, t2 = 0.f, t3 = 0.f;
        for (int list = 0; list < 2; ++list) {
            const unsigned short* ss = list ? s_ld16 : s_lu16;
            int word = poff[list * NN + n];
            int b = word >> 8, deg = word & 255;
            if (deg <= 0) continue;
            int e = b + deg;
            float pa0 = 0.f, pa1 = 0.f, pa2 = 0.f, pa3 = 0.f;
            float pb0 = 0.f, pb1 = 0.f, pb2 = 0.f, pb3 = 0.f;
            float pc0 = 0.f, pc1 = 0.f, pc2 = 0.f, pc3 = 0.f;
            float pd0 = 0.f, pd1 = 0.f, pd2 = 0.f, pd3 = 0.f, den = 0.f;
            for (int cb = b; cb < e; cb += 64) {
                int j  = cb + lane;
                int jc = min(j, e - 1);
                int sl = (int)ss[jc];
                float ex = 0.f;
                if (j < e) { ex = __expf(leaky(ssrc[sl] + sd)); den += ex; }
                int c64 = min(64, e - cb);
                for (int k = 0; k < c64; k += 16) {
                    int i0 = k + grp, i1 = k + 4 + grp;
                    int i2 = k + 8 + grp, i3 = k + 12 + grp;
                    int   s0 = __shfl(sl, i0, 64), s1 = __shfl(sl, i1, 64);
                    int   s2 = __shfl(sl, i2, 64), s3 = __shfl(sl, i3, 64);
                    float w0 = __shfl(ex, i0, 64), w1 = __shfl(ex, i1, 64);
                    float w2 = __shfl(ex, i2, 64), w3 = __shfl(ex, i3, 64);
                    uint2 r0 = *reinterpret_cast<const uint2*>(h16 + (size_t)s0 * 64 + cid * 4);
                    uint2 r1 = *reinterpret_cast<const uint2*>(h16 + (size_t)s1 * 64 + cid * 4);
                    uint2 r2 = *reinterpret_cast<const uint2*>(h16 + (size_t)s2 * 64 + cid * 4);
                    uint2 r3 = *reinterpret_cast<const uint2*>(h16 + (size_t)s3 * 64 + cid * 4);
                    pa0 = fmaf(w0, __uint_as_float(r0.x << 16), pa0);
                    pa1 = fmaf(w0, __uint_as_float(r0.x & 0xFFFF0000u), pa1);
                    pa2 = fmaf(w0, __uint_as_float(r0.y << 16), pa2);
                    pa3 = fmaf(w0, __uint_as_float(r0.y & 0xFFFF0000u), pa3);
                    pb0 = fmaf(w1, __uint_as_float(r1.x << 16), pb0);
                    pb1 = fmaf(w1, __uint_as_float(r1.x & 0xFFFF0000u), pb1);
                    pb2 = fmaf(w1, __uint_as_float(r1.y << 16), pb2);
                    pb3 = fmaf(w1, __uint_as_float(r1.y & 0xFFFF0000u), pb3);
                    pc0 = fmaf(w2, __uint_as_float(r2.x << 16), pc0);
                    pc1 = fmaf(w2, __uint_as_float(r2.x & 0xFFFF0000u), pc1);
                    pc2 = fmaf(w2, __uint_as_float(r2.y << 16), pc2);
                    pc3 = fmaf(w2, __uint_as_float(r2.y & 0xFFFF0000u), pc3);
                    pd0 = fmaf(w3, __uint_as_float(r3.x << 16), pd0);
                    pd1 = fmaf(w3, __uint_as_float(r3.x & 0xFFFF0000u), pd1);
                    pd2 = fmaf(w3, __uint_as_float(r3.y << 16), pd2);
                    pd3 = fmaf(w3, __uint_as_float(r3.y & 0xFFFF0000u), pd3);
                }
            }
#pragma unroll
            for (int o = 32; o; o >>= 1) den += __shfl_xor(den, o, 64);
            float inv = 1.f / (den + 1e-16f);
            float u0 = (pa0 + pb0) + (pc0 + pd0);
            float u1 = (pa1 + pb1) + (pc1 + pd1);
            float u2 = (pa2 + pb2) + (pc2 + pd2);
            float u3 = (pa3 + pb3) + (pc3 + pd3);
            u0 += __shfl_xor(u0, 16, 64); u0 += __shfl_xor(u0, 32, 64);
            u1 += __shfl_xor(u1, 16, 64); u1 += __shfl_xor(u1, 32, 64);
            u2 += __shfl_xor(u2, 16, 64); u2 += __shfl_xor(u2, 32, 64);
            u3 += __shfl_xor(u3, 16, 64); u3 += __shfl_xor(u3, 32, 64);
            t0 = fmaf(u0, inv, t0); t1 = fmaf(u1, inv, t1);
            t2 = fmaf(u2, inv, t2); t3 = fmaf(u3, inv, t3);
        }
        if (lane < 16) {
            float4 o4; o4.x = t0; o4.y = t1; o4.z = t2; o4.w = t3;
            *reinterpret_cast<float4*>(out + (size_t)n * 64 + cid * 4) = o4;
        }
    }
}

// ---------------------------------------------------------------------------
// p-list SpMM gather (touches only hp16); accumulates into out (RMW).
__global__ __launch_bounds__(256) void k_gp(
    const int* __restrict__ poff,
    const unsigned short* __restrict__ c16, const unsigned short* __restrict__ v16,
    const unsigned short* __restrict__ hp16, float* __restrict__ out)
{
    int lane = threadIdx.x & 63;
    int grp  = lane >> 4;
    int cid  = lane & 15;
    int wid  = blockIdx.x * (blockDim.x >> 6) + (threadIdx.x >> 6);
    int nw   = gridDim.x * (blockDim.x >> 6);
    for (int n = wid; n < NN; n += nw) {
        int word = poff[2 * NN + n];
        int b = word >> 8, deg = word & 255;
        float pa0 = 0.f, pa1 = 0.f, pa2 = 0.f, pa3 = 0.f;
        float pb0 = 0.f, pb1 = 0.f, pb2 = 0.f, pb3 = 0.f;
        float pc0 = 0.f, pc1 = 0.f, pc2 = 0.f, pc3 = 0.f;
        float pd0 = 0.f, pd1 = 0.f, pd2 = 0.f, pd3 = 0.f;
        int e = b + deg;
        for (int cb = b; cb < e; cb += 64) {
            int j  = cb + lane;
            int jc = min(j, e - 1);
            int cl = (int)c16[jc];
            float vl = (j < e) ? bf2f(v16[jc]) : 0.f;
            int c64 = min(64, e - cb);
            for (int k = 0; k < c64; k += 16) {
                int i0 = k + grp, i1 = k + 4 + grp;
                int i2 = k + 8 + grp, i3 = k + 12 + grp;
                int   s0 = __shfl(cl, i0, 64), s1 = __shfl(cl, i1, 64);
                int   s2 = __shfl(cl, i2, 64), s3 = __shfl(cl, i3, 64);
                float w0 = __shfl(vl, i0, 64), w1 = __shfl(vl, i1, 64);
                float w2 = __shfl(vl, i2, 64), w3 = __shfl(vl, i3, 64);
                uint2 r0 = *reinterpret_cast<const uint2*>(hp16 + (size_t)s0 * 64 + cid * 4);
                uint2 r1 = *reinterpret_cast<const uint2*>(hp16 + (size_t)s1 * 64 + cid * 4);
                uint2 r2 = *reinterpret_cast<const uint2*>(hp16 + (size_t)s2 * 64 + cid * 4);
                uint2 r3 = *reinterpret_cast<const uint2*>(hp16 + (size_t)s3 * 64 + cid * 4);
                pa0 = fmaf(w0, __uint_as_float(r0.x << 16), pa0);
                pa1 = fmaf(w0, __uint_as_float(r0.x & 0xFFFF0000u), pa1);
                pa2 = fmaf(w0, __uint_as_float(r0.y << 16), pa2);
                pa3 = fmaf(w0, __uint_as_float(r0.y & 0xFFFF0000u), pa3);
                pb0 = fmaf(w1, __uint_as_float(r1.x << 16), pb0);
                pb1 = fmaf(w1, __uint_as_float(r1.x & 0xFFFF0000u), pb1);
                pb2 = fmaf(w1, __uint_as_float(r1.y << 16), pb2);
                pb3 = fmaf(w1, __uint_as_float(r1.y & 0xFFFF0000u), pb3);
                pc0 = fmaf(w2, __uint_as_float(r2.x << 16), pc0);
                pc1 = fmaf(w2, __uint_as_float(r2.x & 0xFFFF0000u), pc1);
                pc2 = fmaf(w2, __uint_as_float(r2.y << 16), pc2);
                pc3 = fmaf(w2, __uint_as_float(r2.y & 0xFFFF0000u), pc3);
                pd0 = fmaf(w3, __uint_as_float(r3.x << 16), pd0);
                pd1 = fmaf(w3, __uint_as_float(r3.x & 0xFFFF0000u), pd1);
                pd2 = fmaf(w3, __uint_as_float(r3.y << 16), pd2);
                pd3 = fmaf(w3, __uint_as_float(r3.y & 0xFFFF0000u), pd3);
            }
        }
        float u0 = (pa0 + pb0) + (pc0 + pd0);
        float u1 = (pa1 + pb1) + (pc1 + pd1);
        float u2 = (pa2 + pb2) + (pc2 + pd2);
        float u3 = (pa3 + pb3) + (pc3 + pd3);
        u0 += __shfl_xor(u0, 16, 64); u0 += __shfl_xor(u0, 32, 64);
        u1 += __shfl_xor(u1, 16, 64); u1 += __shfl_xor(u1, 32, 64);
        u2 += __shfl_xor(u2, 16, 64); u2 += __shfl_xor(u2, 32, 64);
        u3 += __shfl_xor(u3, 16, 64); u3 += __shfl_xor(u3, 32, 64);
        if (lane < 16) {
            float4 o4 = *reinterpret_cast<float4*>(out + (size_t)n * 64 + cid * 4);
            o4.x += u0; o4.y += u1; o4.z += u2; o4.w += u3;
            *reinterpret_cast<float4*>(out + (size_t)n * 64 + cid * 4) = o4;
        }
    }
}

// ---------------------------------------------------------------------------
extern "C" void kernel_launch(void* const* d_in, const int* in_sizes, int n_in,
                              void* d_out, int out_size, void* d_ws, size_t ws_size,
                              hipStream_t stream)
{
    const float* feat = (const float*)d_in[0];
    const float* Wg   = (const float*)d_in[1];
    const float* bg   = (const float*)d_in[2];
    const float* as_  = (const float*)d_in[3];
    const float* ad_  = (const float*)d_in[4];
    const float* Wp   = (const float*)d_in[5];
    const float* bp   = (const float*)d_in[6];
    const float* pv   = (const float*)d_in[7];
    const int*   lu   = (const int*)d_in[8];
    const int*   ld   = (const int*)d_in[9];
    const int*   pi   = (const int*)d_in[10];
    float* out = (float*)d_out;

    unsigned short* h16  = (unsigned short*)d_ws;        // NN*64 ushort
    unsigned short* hp16 = h16 + (size_t)NN * 64;        // NN*64 ushort
    float* fbase = (float*)(hp16 + (size_t)NN * 64);
    float* ssrc  = fbase;                                // NN
    float* sdst  = ssrc + NN;                            // NN
    int*   poff  = (int*)(sdst + NN);                    // 3*NN packed (start<<8|deg)
    int*   cnt   = poff + 3 * NN;                        // 3*NBK*16 (64B-padded)
    unsigned* bglu = (unsigned*)(cnt + 3 * NBK * 16);    // NBK*CAPB
    unsigned* bgld = bglu + (size_t)NBK * CAPB;          // NBK*CAPB
    unsigned* bgpc = bgld + (size_t)NBK * CAPB;          // NBK*CAPB
    unsigned short* bgpv  = (unsigned short*)(bgpc + (size_t)NBK * CAPB); // NBK*CAPB us
    unsigned short* s_lu16 = bgpv + (size_t)NBK * CAPB;  // NBK*CAPB ushort
    unsigned short* s_ld16 = s_lu16 + (size_t)NBK * CAPB;
    unsigned short* c16    = s_ld16 + (size_t)NBK * CAPB;
    unsigned short* v16    = c16 + (size_t)NBK * CAPB;

    hipLaunchKernelGGL(k_gemm, dim3(782), dim3(256), 0, stream,
                       feat, Wg, bg, as_, ad_, Wp, bp, h16, hp16, ssrc, sdst, cnt);
    hipLaunchKernelGGL(k_bin, dim3(3 * NT), dim3(512), 0, stream,
                       lu, ld, pi, pv, cnt, bglu, bgld, bgpc, bgpv);
    hipLaunchKernelGGL(k_b2c, dim3(3 * NBK), dim3(512), 0, stream,
                       cnt, bglu, bgld, bgpc, bgpv, s_lu16, s_ld16, c16, v16, poff);
    hipLaunchKernelGGL(k_ggat, dim3(2048), dim3(256), 0, stream,
                       poff, s_lu16, s_ld16, ssrc, sdst, h16, out);
    hipLaunchKernelGGL(k_gp, dim3(2048), dim3(256), 0, stream,
                       poff, c16, v16, hp16, out);
}

// Round 16
// 151.130 us; speedup vs baseline: 1.6845x; 1.1406x over previous
//
#include <hip/hip_runtime.h>
#include <cfloat>

#define NN 50000
#define EE 1600000
#define NEG 0.2f
#define BSH 7
#define BSZ 128                       // nodes per bucket
#define NBK ((NN + BSZ - 1) / BSZ)    // 391
#define CAPB 4608                     // fixed bucket capacity (mean 4096 + 8 sigma)
#define TSZ 8192                      // k_bin tile size (edges)
#define NT  ((EE + TSZ - 1) / TSZ)    // 196 tiles per list
#define NTILE (NN / 16)               // 3125 gemm tiles
#define GEMM_BLKS ((NTILE + 7) / 8)   // 391

typedef __attribute__((ext_vector_type(8))) short short8;
typedef __attribute__((ext_vector_type(4))) float f32x4;

__device__ inline float leaky(float v) { return v >= 0.f ? v : NEG * v; }

__device__ inline unsigned short f2bf(float f) {
    unsigned u = __float_as_uint(f);
    u += 0x7FFFu + ((u >> 16) & 1u);          // round-to-nearest-even
    return (unsigned short)(u >> 16);
}
__device__ inline float bf2f(unsigned short s) {
    return __uint_as_float(((unsigned)s) << 16);
}

// ---------------------------------------------------------------------------
// Heterogeneous dispatch: blocks [0, 3*NT) run the bucket-binning pass;
// blocks [3*NT, 3*NT+GEMM_BLKS) run the MFMA GEMM (independent work).
__global__ __launch_bounds__(512, 8) void k_gb(
    const float* __restrict__ feat, const float* __restrict__ Wg,
    const float* __restrict__ bg, const float* __restrict__ as_,
    const float* __restrict__ ad_, const float* __restrict__ Wp,
    const float* __restrict__ bp,
    unsigned short* __restrict__ h16, unsigned short* __restrict__ hp16,
    float* __restrict__ ssrc, float* __restrict__ sdst,
    const int* __restrict__ lu, const int* __restrict__ ld,
    const int* __restrict__ pi, const float* __restrict__ pv,
    int* __restrict__ cnt,
    unsigned* __restrict__ bglu, unsigned* __restrict__ bgld,
    unsigned* __restrict__ bgpc, unsigned short* __restrict__ bgpv)
{
    __shared__ union {
        struct { unsigned short wg[4096]; unsigned short wp[4096]; } g;
        struct { int hist[NBK]; int loff[NBK]; int gbase[NBK];
                 int part[512]; unsigned stage[TSZ]; } b;
    } sm;
    int t = threadIdx.x;

    if (blockIdx.x >= 3 * NT) {
        // ----------------- GEMM part -----------------
        int gbid = blockIdx.x - 3 * NT;
        for (int i = t; i < 4096; i += 512) {
            int k = i >> 6, o = i & 63;            // W[k][o] -> WT[o][k]
            sm.g.wg[o * 64 + k] = f2bf(Wg[i]);
            sm.g.wp[o * 64 + k] = f2bf(Wp[i]);
        }
        __syncthreads();
        int lane = t & 63, w = t >> 6;
        int tile = gbid * 8 + w;
        if (tile >= NTILE) return;
        int n0 = tile * 16;
        int m = lane & 15, g = lane >> 4;
        const float* frow = feat + (size_t)(n0 + m) * 64 + g * 8;
        float4 fa = *reinterpret_cast<const float4*>(frow);
        float4 fb = *reinterpret_cast<const float4*>(frow + 4);
        float4 fc = *reinterpret_cast<const float4*>(frow + 32);
        float4 fd = *reinterpret_cast<const float4*>(frow + 36);
        short8 a0, a1;
        a0[0]=(short)f2bf(fa.x); a0[1]=(short)f2bf(fa.y); a0[2]=(short)f2bf(fa.z); a0[3]=(short)f2bf(fa.w);
        a0[4]=(short)f2bf(fb.x); a0[5]=(short)f2bf(fb.y); a0[6]=(short)f2bf(fb.z); a0[7]=(short)f2bf(fb.w);
        a1[0]=(short)f2bf(fc.x); a1[1]=(short)f2bf(fc.y); a1[2]=(short)f2bf(fc.z); a1[3]=(short)f2bf(fc.w);
        a1[4]=(short)f2bf(fd.x); a1[5]=(short)f2bf(fd.y); a1[6]=(short)f2bf(fd.z); a1[7]=(short)f2bf(fd.w);
        float ps[4] = {0.f,0.f,0.f,0.f}, pd[4] = {0.f,0.f,0.f,0.f};
#pragma unroll
        for (int tc = 0; tc < 4; ++tc) {
            const unsigned short* bgp = &sm.g.wg[(16 * tc + m) * 64 + g * 8];
            short8 b0 = *reinterpret_cast<const short8*>(bgp);
            short8 b1 = *reinterpret_cast<const short8*>(bgp + 32);
            f32x4 c = {0.f, 0.f, 0.f, 0.f};
            c = __builtin_amdgcn_mfma_f32_16x16x32_bf16(a0, b0, c, 0, 0, 0);
            c = __builtin_amdgcn_mfma_f32_16x16x32_bf16(a1, b1, c, 0, 0, 0);
            const unsigned short* bpp = &sm.g.wp[(16 * tc + m) * 64 + g * 8];
            short8 d0 = *reinterpret_cast<const short8*>(bpp);
            short8 d1 = *reinterpret_cast<const short8*>(bpp + 32);
            f32x4 e = {0.f, 0.f, 0.f, 0.f};
            e = __builtin_amdgcn_mfma_f32_16x16x32_bf16(a0, d0, e, 0, 0, 0);
            e = __builtin_amdgcn_mfma_f32_16x16x32_bf16(a1, d1, e, 0, 0, 0);
            int col = 16 * tc + m;
            float bgv = bg[col], bpv = bp[col];
            float asv = as_[col], adv = ad_[col];
#pragma unroll
            for (int r = 0; r < 4; ++r) {
                float hv = c[r] + bgv;
                int row = n0 + g * 4 + r;
                h16[(size_t)row * 64 + col] = f2bf(hv);
                ps[r] = fmaf(hv, asv, ps[r]);
                pd[r] = fmaf(hv, adv, pd[r]);
                float pv2 = e[r] + bpv;
                hp16[(size_t)row * 64 + col] = f2bf(pv2);
            }
        }
#pragma unroll
        for (int o = 1; o < 16; o <<= 1) {
#pragma unroll
            for (int r = 0; r < 4; ++r) {
                ps[r] += __shfl_xor(ps[r], o, 64);
                pd[r] += __shfl_xor(pd[r], o, 64);
            }
        }
        if (m == 0) {
#pragma unroll
            for (int r = 0; r < 4; ++r) {
                ssrc[n0 + g * 4 + r] = ps[r];
                sdst[n0 + g * 4 + r] = pd[r];
            }
        }
        return;
    }

    // ----------------- BIN part -----------------
    int task = blockIdx.x;
    int list = task / NT, tile = task - list * NT;
    int e0 = tile * TSZ, e1 = min(e0 + TSZ, EE), sz = e1 - e0;
    const int* srcp; const int* dstp;
    if (list == 0)      { srcp = lu;      dstp = lu + EE; }
    else if (list == 1) { srcp = ld;      dstp = ld + EE; }
    else                { srcp = pi + EE; dstp = pi; }
    for (int i = t; i < NBK; i += 512) sm.b.hist[i] = 0;
    __syncthreads();
    for (int i = t; i < sz; i += 512)
        atomicAdd(&sm.b.hist[dstp[e0 + i] >> BSH], 1);
    __syncthreads();
    {
        int s = (t < NBK) ? sm.b.hist[t] : 0;
        sm.b.part[t] = s;
        __syncthreads();
        for (int d = 1; d < 512; d <<= 1) {
            int v = 0;
            if (t >= d) v = sm.b.part[t - d];
            __syncthreads();
            if (t >= d) sm.b.part[t] += v;
            __syncthreads();
        }
        if (t < NBK) sm.b.loff[t] = sm.b.part[t] - s;    // exclusive
    }
    __syncthreads();
    for (int i = t; i < NBK; i += 512) {
        int c = sm.b.hist[i];
        if (c) {
            int pos = atomicAdd(&cnt[(list * NBK + i) * 16], c);
            sm.b.gbase[i] = i * CAPB + pos;
        }
        sm.b.hist[i] = sm.b.loff[i];
    }
    __syncthreads();
    if (list == 2) {
        for (int i = t; i < sz; i += 512) {
            int d = dstp[e0 + i];
            unsigned pay = (unsigned)i | ((unsigned)d << 16);
            int r = atomicAdd(&sm.b.hist[d >> BSH], 1);
            sm.b.stage[r] = pay;
        }
        __syncthreads();
        for (int i = t; i < sz; i += 512) {
            unsigned v = sm.b.stage[i];
            int b = (int)(v >> (16 + BSH));
            int li = (int)(v & 0xFFFFu);
            int addr = sm.b.gbase[b] + (i - sm.b.loff[b]);
            bgpc[addr] = (unsigned)srcp[e0 + li] | (v & 0xFFFF0000u);
            bgpv[addr] = f2bf(pv[e0 + li]);
        }
    } else {
        for (int i = t; i < sz; i += 512) {
            int d = dstp[e0 + i];
            unsigned pay = (unsigned)srcp[e0 + i] | ((unsigned)d << 16);
            int r = atomicAdd(&sm.b.hist[d >> BSH], 1);
            sm.b.stage[r] = pay;
        }
        __syncthreads();
        unsigned* arr = list ? bgld : bglu;
        for (int i = t; i < sz; i += 512) {
            unsigned v = sm.b.stage[i];
            int b = (int)(v >> (16 + BSH));
            arr[sm.b.gbase[b] + (i - sm.b.loff[b])] = v;
        }
    }
}

// ---------------------------------------------------------------------------
// per-(list,bucket): refine bucket region to per-node CSR; emits packed
// poff = (region_start<<8)|deg, ushort src for GAT, cv32 = col|val<<16 for p.
__global__ __launch_bounds__(512) void k_b2c(
    const int* __restrict__ cnt,
    const unsigned* __restrict__ bglu, const unsigned* __restrict__ bgld,
    const unsigned* __restrict__ bgpc, const unsigned short* __restrict__ bgpv,
    unsigned short* __restrict__ s_lu16, unsigned short* __restrict__ s_ld16,
    unsigned* __restrict__ cv32, int* __restrict__ poff)
{
    __shared__ int ecnt[BSZ];
    __shared__ int scn[BSZ];
    __shared__ unsigned buf[CAPB];
    __shared__ unsigned short bufv[CAPB];
    int bid  = blockIdx.x;
    int list = bid / NBK, b = bid - list * NBK;
    int size = min(cnt[(list * NBK + b) * 16], CAPB);
    int base = b * CAPB;
    int t = threadIdx.x;
    if (t < BSZ) ecnt[t] = 0;
    __syncthreads();
    const unsigned* arr = (list == 0) ? bglu : (list == 1) ? bgld : bgpc;
    for (int i = t; i < size; i += 512) {
        unsigned v = arr[base + i];
        buf[i] = v;
        if (list == 2) bufv[i] = bgpv[base + i];
        atomicAdd(&ecnt[(v >> 16) & (BSZ - 1)], 1);
    }
    __syncthreads();
    if (t < BSZ) scn[t] = ecnt[t];
    __syncthreads();
    for (int d = 1; d < BSZ; d <<= 1) {
        int add = 0;
        if (t < BSZ && t >= d) add = scn[t - d];
        __syncthreads();
        if (t < BSZ && t >= d) scn[t] += add;
        __syncthreads();
    }
    int n0 = b << BSH;
    if (t < BSZ) {
        int deg  = ecnt[t];
        int excl = scn[t] - deg;
        if (n0 + t < NN)
            poff[list * NN + n0 + t] = ((base + excl) << 8) | deg;
    }
    __syncthreads();
    if (t < BSZ) ecnt[t] = scn[t] - ecnt[t];     // cursors
    __syncthreads();
    if (list == 2) {
        for (int i = t; i < size; i += 512) {
            unsigned v = buf[i];
            int pos = atomicAdd(&ecnt[(v >> 16) & (BSZ - 1)], 1);
            cv32[base + pos] = (v & 0xFFFFu) | ((unsigned)bufv[i] << 16);
        }
    } else {
        unsigned short* o16 = list ? s_ld16 : s_lu16;
        for (int i = t; i < size; i += 512) {
            unsigned v = buf[i];
            int pos = atomicAdd(&ecnt[(v >> 16) & (BSZ - 1)], 1);
            o16[base + pos] = (unsigned short)(v & 0xFFFFu);
        }
    }
}

// ---------------------------------------------------------------------------
// GAT gather (lu+ld only; touches only h16). Packed src|bf16(w)<<16 payload:
// one shfl per edge-slot. 16 edges/iter via 4 independent uint2 loads.
__global__ __launch_bounds__(256) void k_ggat(
    const int* __restrict__ poff,
    const unsigned short* __restrict__ s_lu16, const unsigned short* __restrict__ s_ld16,
    const float* __restrict__ ssrc, const float* __restrict__ sdst,
    const unsigned short* __restrict__ h16, float* __restrict__ out)
{
    int lane = threadIdx.x & 63;
    int grp  = lane >> 4;            // edge subgroup 0..3
    int cid  = lane & 15;            // channel-quad id
    int wid  = blockIdx.x * (blockDim.x >> 6) + (threadIdx.x >> 6);
    int nw   = gridDim.x * (blockDim.x >> 6);
    for (int n = wid; n < NN; n += nw) {
        float sd = sdst[n];
        float t0 = 0.f, t1 = 0.f, t2 = 0.f, t3 = 0.f;
        for (int list = 0; list < 2; ++list) {
            const unsigned short* ss = list ? s_ld16 : s_lu16;
            int word = poff[list * NN + n];
            int b = word >> 8, deg = word & 255;
            if (deg <= 0) continue;
            int e = b + deg;
            float pa0 = 0.f, pa1 = 0.f, pa2 = 0.f, pa3 = 0.f;
            float pb0 = 0.f, pb1 = 0.f, pb2 = 0.f, pb3 = 0.f;
            float pc0 = 0.f, pc1 = 0.f, pc2 = 0.f, pc3 = 0.f;
            float pd0 = 0.f, pd1 = 0.f, pd2 = 0.f, pd3 = 0.f, den = 0.f;
            for (int cb = b; cb < e; cb += 64) {
                int j  = cb + lane;
                int jc = min(j, e - 1);
                int sl = (int)ss[jc];
                float ex = 0.f;
                if (j < e) { ex = __expf(leaky(ssrc[sl] + sd)); den += ex; }
                unsigned pk = (unsigned)sl | ((unsigned)f2bf(ex) << 16);
                int c64 = min(64, e - cb);
                for (int k = 0; k < c64; k += 16) {
                    int i0 = k + grp, i1 = k + 4 + grp;
                    int i2 = k + 8 + grp, i3 = k + 12 + grp;
                    unsigned q0 = (unsigned)__shfl((int)pk, i0, 64);
                    unsigned q1 = (unsigned)__shfl((int)pk, i1, 64);
                    unsigned q2 = (unsigned)__shfl((int)pk, i2, 64);
                    unsigned q3 = (unsigned)__shfl((int)pk, i3, 64);
                    int   s0 = (int)(q0 & 0xFFFFu), s1 = (int)(q1 & 0xFFFFu);
                    int   s2 = (int)(q2 & 0xFFFFu), s3 = (int)(q3 & 0xFFFFu);
                    float w0 = __uint_as_float(q0 & 0xFFFF0000u);
                    float w1 = __uint_as_float(q1 & 0xFFFF0000u);
                    float w2 = __uint_as_float(q2 & 0xFFFF0000u);
                    float w3 = __uint_as_float(q3 & 0xFFFF0000u);
                    uint2 r0 = *reinterpret_cast<const uint2*>(h16 + (size_t)s0 * 64 + cid * 4);
                    uint2 r1 = *reinterpret_cast<const uint2*>(h16 + (size_t)s1 * 64 + cid * 4);
                    uint2 r2 = *reinterpret_cast<const uint2*>(h16 + (size_t)s2 * 64 + cid * 4);
                    uint2 r3 = *reinterpret_cast<const uint2*>(h16 + (size_t)s3 * 64 + cid * 4);
                    pa0 = fmaf(w0, __uint_as_float(r0.x << 16), pa0);
                    pa1 = fmaf(w0, __uint_as_float(r0.x & 0xFFFF0000u), pa1);
                    pa2 = fmaf(w0, __uint_as_float(r0.y << 16), pa2);
                    pa3 = fmaf(w0, __uint_as_float(r0.y & 0xFFFF0000u), pa3);
                    pb0 = fmaf(w1, __uint_as_float(r1.x << 16), pb0);
                    pb1 = fmaf(w1, __uint_as_float(r1.x & 0xFFFF0000u), pb1);
                    pb2 = fmaf(w1, __uint_as_float(r1.y << 16), pb2);
                    pb3 = fmaf(w1, __uint_as_float(r1.y & 0xFFFF0000u), pb3);
                    pc0 = fmaf(w2, __uint_as_float(r2.x << 16), pc0);
                    pc1 = fmaf(w2, __uint_as_float(r2.x & 0xFFFF0000u), pc1);
                    pc2 = fmaf(w2, __uint_as_float(r2.y << 16), pc2);
                    pc3 = fmaf(w2, __uint_as_float(r2.y & 0xFFFF0000u), pc3);
                    pd0 = fmaf(w3, __uint_as_float(r3.x << 16), pd0);
                    pd1 = fmaf(w3, __uint_as_float(r3.x & 0xFFFF0000u), pd1);
                    pd2 = fmaf(w3, __uint_as_float(r3.y << 16), pd2);
                    pd3 = fmaf(w3, __uint_as_float(r3.y & 0xFFFF0000u), pd3);
                }
            }
#pragma unroll
            for (int o = 32; o; o >>= 1) den += __shfl_xor(den, o, 64);
            float inv = 1.f / (den + 1e-16f);
            float u0 = (pa0 + pb0) + (pc0 + pd0);
            float u1 = (pa1 + pb1) + (pc1 + pd1);
            float u2 = (pa2 + pb2) + (pc2 + pd2);
            float u3 = (pa3 + pb3) + (pc3 + pd3);
            u0 += __shfl_xor(u0, 16, 64); u0 += __shfl_xor(u0, 32, 64);
            u1 += __shfl_xor(u1, 16, 64); u1 += __shfl_xor(u1, 32, 64);
            u2 += __shfl_xor(u2, 16, 64); u2 += __shfl_xor(u2, 32, 64);
            u3 += __shfl_xor(u3, 16, 64); u3 += __shfl_xor(u3, 32, 64);
            t0 = fmaf(u0, inv, t0); t1 = fmaf(u1, inv, t1);
            t2 = fmaf(u2, inv, t2); t3 = fmaf(u3, inv, t3);
        }
        if (lane < 16) {
            float4 o4; o4.x = t0; o4.y = t1; o4.z = t2; o4.w = t3;
            *reinterpret_cast<float4*>(out + (size_t)n * 64 + cid * 4) = o4;
        }
    }
}

// ---------------------------------------------------------------------------
// p-list SpMM gather (touches only hp16); packed cv32 = col|bf16(val)<<16.
__global__ __launch_bounds__(256) void k_gp(
    const int* __restrict__ poff, const unsigned* __restrict__ cv32,
    const unsigned short* __restrict__ hp16, float* __restrict__ out)
{
    int lane = threadIdx.x & 63;
    int grp  = lane >> 4;
    int cid  = lane & 15;
    int wid  = blockIdx.x * (blockDim.x >> 6) + (threadIdx.x >> 6);
    int nw   = gridDim.x * (blockDim.x >> 6);
    for (int n = wid; n < NN; n += nw) {
        int word = poff[2 * NN + n];
        int b = word >> 8, deg = word & 255;
        float pa0 = 0.f, pa1 = 0.f, pa2 = 0.f, pa3 = 0.f;
        float pb0 = 0.f, pb1 = 0.f, pb2 = 0.f, pb3 = 0.f;
        float pc0 = 0.f, pc1 = 0.f, pc2 = 0.f, pc3 = 0.f;
        float pd0 = 0.f, pd1 = 0.f, pd2 = 0.f, pd3 = 0.f;
        int e = b + deg;
        for (int cb = b; cb < e; cb += 64) {
            int j  = cb + lane;
            int jc = min(j, e - 1);
            unsigned cv = cv32[jc];
            if (j >= e) cv &= 0xFFFFu;           // zero the value half on tail
            int c64 = min(64, e - cb);
            for (int k = 0; k < c64; k += 16) {
                int i0 = k + grp, i1 = k + 4 + grp;
                int i2 = k + 8 + grp, i3 = k + 12 + grp;
                unsigned q0 = (unsigned)__shfl((int)cv, i0, 64);
                unsigned q1 = (unsigned)__shfl((int)cv, i1, 64);
                unsigned q2 = (unsigned)__shfl((int)cv, i2, 64);
                unsigned q3 = (unsigned)__shfl((int)cv, i3, 64);
                int   s0 = (int)(q0 & 0xFFFFu), s1 = (int)(q1 & 0xFFFFu);
                int   s2 = (int)(q2 & 0xFFFFu), s3 = (int)(q3 & 0xFFFFu);
                float w0 = __uint_as_float(q0 & 0xFFFF0000u);
                float w1 = __uint_as_float(q1 & 0xFFFF0000u);
                float w2 = __uint_as_float(q2 & 0xFFFF0000u);
                float w3 = __uint_as_float(q3 & 0xFFFF0000u);
                uint2 r0 = *reinterpret_cast<const uint2*>(hp16 + (size_t)s0 * 64 + cid * 4);
                uint2 r1 = *reinterpret_cast<const uint2*>(hp16 + (size_t)s1 * 64 + cid * 4);
                uint2 r2 = *reinterpret_cast<const uint2*>(hp16 + (size_t)s2 * 64 + cid * 4);
                uint2 r3 = *reinterpret_cast<const uint2*>(hp16 + (size_t)s3 * 64 + cid * 4);
                pa0 = fmaf(w0, __uint_as_float(r0.x << 16), pa0);
                pa1 = fmaf(w0, __uint_as_float(r0.x & 0xFFFF0000u), pa1);
                pa2 = fmaf(w0, __uint_as_float(r0.y << 16), pa2);
                pa3 = fmaf(w0, __uint_as_float(r0.y & 0xFFFF0000u), pa3);
                pb0 = fmaf(w1, __uint_as_float(r1.x << 16), pb0);
                pb1 = fmaf(w1, __uint_as_float(r1.x & 0xFFFF0000u), pb1);
                pb2 = fmaf(w1, __uint_as_float(r1.y << 16), pb2);
                pb3 = fmaf(w1, __uint_as_float(r1.y & 0xFFFF0000u), pb3);
                pc0 = fmaf(w2, __uint_as_float(r2.x << 16), pc0);
                pc1 = fmaf(w2, __uint_as_float(r2.x & 0xFFFF0000u), pc1);
                pc2 = fmaf(w2, __uint_as_float(r2.y << 16), pc2);
                pc3 = fmaf(w2, __uint_as_float(r2.y & 0xFFFF0000u), pc3);
                pd0 = fmaf(w3, __uint_as_float(r3.x << 16), pd0);
                pd1 = fmaf(w3, __uint_as_float(r3.x & 0xFFFF0000u), pd1);
                pd2 = fmaf(w3, __uint_as_float(r3.y << 16), pd2);
                pd3 = fmaf(w3, __uint_as_float(r3.y & 0xFFFF0000u), pd3);
            }
        }
        float u0 = (pa0 + pb0) + (pc0 + pd0);
        float u1 = (pa1 + pb1) + (pc1 + pd1);
        float u2 = (pa2 + pb2) + (pc2 + pd2);
        float u3 = (pa3 + pb3) + (pc3 + pd3);
        u0 += __shfl_xor(u0, 16, 64); u0 += __shfl_xor(u0, 32, 64);
        u1 += __shfl_xor(u1, 16, 64); u1 += __shfl_xor(u1, 32, 64);
        u2 += __shfl_xor(u2, 16, 64); u2 += __shfl_xor(u2, 32, 64);
        u3 += __shfl_xor(u3, 16, 64); u3 += __shfl_xor(u3, 32, 64);
        if (lane < 16) {
            float4 o4 = *reinterpret_cast<float4*>(out + (size_t)n * 64 + cid * 4);
            o4.x += u0; o4.y += u1; o4.z += u2; o4.w += u3;
            *reinterpret_cast<float4*>(out + (size_t)n * 64 + cid * 4) = o4;
        }
    }
}

// ---------------------------------------------------------------------------
extern "C" void kernel_launch(void* const* d_in, const int* in_sizes, int n_in,
                              void* d_out, int out_size, void* d_ws, size_t ws_size,
                              hipStream_t stream)
{
    const float* feat = (const float*)d_in[0];
    const float* Wg   = (const float*)d_in[1];
    const float* bg   = (const float*)d_in[2];
    const float* as_  = (const float*)d_in[3];
    const float* ad_  = (const float*)d_in[4];
    const float* Wp   = (const float*)d_in[5];
    const float* bp   = (const float*)d_in[6];
    const float* pv   = (const float*)d_in[7];
    const int*   lu   = (const int*)d_in[8];
    const int*   ld   = (const int*)d_in[9];
    const int*   pi   = (const int*)d_in[10];
    float* out = (float*)d_out;

    unsigned short* h16  = (unsigned short*)d_ws;        // NN*64 ushort
    unsigned short* hp16 = h16 + (size_t)NN * 64;        // NN*64 ushort
    float* fbase = (float*)(hp16 + (size_t)NN * 64);
    float* ssrc  = fbase;                                // NN
    float* sdst  = ssrc + NN;                            // NN
    int*   poff  = (int*)(sdst + NN);                    // 3*NN packed (start<<8|deg)
    int*   cnt   = poff + 3 * NN;                        // 3*NBK*16 (64B-padded)
    unsigned* bglu = (unsigned*)(cnt + 3 * NBK * 16);    // NBK*CAPB
    unsigned* bgld = bglu + (size_t)NBK * CAPB;          // NBK*CAPB
    unsigned* bgpc = bgld + (size_t)NBK * CAPB;          // NBK*CAPB
    unsigned short* bgpv  = (unsigned short*)(bgpc + (size_t)NBK * CAPB); // NBK*CAPB us
    unsigned short* s_lu16 = bgpv + (size_t)NBK * CAPB;  // NBK*CAPB ushort
    unsigned short* s_ld16 = s_lu16 + (size_t)NBK * CAPB;
    unsigned* cv32 = (unsigned*)(s_ld16 + (size_t)NBK * CAPB);  // NBK*CAPB uint

    hipMemsetAsync(cnt, 0, (size_t)(3 * NBK * 16) * sizeof(int), stream);
    hipLaunchKernelGGL(k_gb, dim3(3 * NT + GEMM_BLKS), dim3(512), 0, stream,
                       feat, Wg, bg, as_, ad_, Wp, bp, h16, hp16, ssrc, sdst,
                       lu, ld, pi, pv, cnt, bglu, bgld, bgpc, bgpv);
    hipLaunchKernelGGL(k_b2c, dim3(3 * NBK), dim3(512), 0, stream,
                       cnt, bglu, bgld, bgpc, bgpv, s_lu16, s_ld16, cv32, poff);
    hipLaunchKernelGGL(k_ggat, dim3(2048), dim3(256), 0, stream,
                       poff, s_lu16, s_ld16, ssrc, sdst, h16, out);
    hipLaunchKernelGGL(k_gp, dim3(2048), dim3(256), 0, stream,
                       poff, cv32, hp16, out);
}